// Round 1
// baseline (748.610 us; speedup 1.0000x reference)
//
#include <hip/hip_runtime.h>
#include <math.h>

namespace {

constexpr int kN = 256, kV = 256, kH = 256, kLat = 64, kOut = 128;
constexpr int kGin = 2 * kH + kLat;   // 576
constexpr int kH2  = 2 * kH;          // 512
constexpr int kNV  = kN * kV;         // 65536
constexpr float kEps = 1e-5f;

// workspace layout (float offsets)
constexpr size_t offH   = 0;                                // h, later reused as y
constexpr size_t offHP  = offH  + (size_t)kNV * kH;         // h_prime
constexpr size_t offHA1 = offHP + (size_t)kNV * kH;
constexpr size_t offHA2 = offHA1 + kNV;
constexpr size_t offM   = offHA2 + kNV;                     // softmax row max
constexpr size_t offRD  = offM   + kNV;                     // softmax 1/denom
constexpr size_t offST  = offRD  + kNV;                     // stats block (1536 floats)
// stats sublayout
// [0,256) sum1 | [256,512) sumsq1 | [512,768) scale1 | [768,1024) shift1
// [1024,1152) sum2 | [1152,1280) sumsq2 | [1280,1408) scale2 | [1408,1536) shift2

__global__ __launch_bounds__(256) void k0_zero(float* __restrict__ st) {
  const int t = threadIdx.x;
  st[t] = 0.f;          // sum1
  st[256 + t] = 0.f;    // sumsq1
  st[1024 + t] = 0.f;   // sum2 + sumsq2 (256 floats)
}

// ---- K1: per-row se/ve/comb, then h = comb @ Wg -------------------------
__global__ __launch_bounds__(256) void k1_encode(
    const float* __restrict__ obs, const float* __restrict__ hi,
    const float* __restrict__ Ws, const float* __restrict__ bs,
    const float* __restrict__ Wv, const float* __restrict__ bv,
    const float* __restrict__ Wg, float* __restrict__ h)
{
  __shared__ float comb[32][kGin];   // 73.7 KB
  const int t = threadIdx.x;
  const int r0 = blockIdx.x * 32;
  const float ws0 = Ws[t], ws1 = Ws[kH + t], bsv = bs[t];
  const float wv0 = Wv[t], wv1 = Wv[kH + t], bvv = bv[t];
  for (int r = 0; r < 32; ++r) {
    const int row = r0 + r;
    const float o1 = obs[row*5+1], o2 = obs[row*5+2];
    const float o3 = obs[row*5+3], o4 = obs[row*5+4];
    float s = fmaf(o2, ws1, fmaf(o1, ws0, bsv));
    comb[r][t] = s > 0.f ? s : 0.f;
    float v = fmaf(o4, wv1, fmaf(o3, wv0, bvv));
    comb[r][kH + t] = v > 0.f ? v : 0.f;
    if (t < kLat) comb[r][2*kH + t] = hi[(size_t)row * kLat + t];
  }
  __syncthreads();

  const int rg = t >> 6, cl = t & 63;
  float acc[8][4];
#pragma unroll
  for (int i = 0; i < 8; ++i)
#pragma unroll
    for (int q = 0; q < 4; ++q) acc[i][q] = 0.f;

  for (int j0 = 0; j0 < kGin; j0 += 4) {
    float4 c[8];
#pragma unroll
    for (int i = 0; i < 8; ++i)
      c[i] = *reinterpret_cast<const float4*>(&comb[rg*8 + i][j0]);
    float w0[4], w1[4], w2[4], w3[4];
#pragma unroll
    for (int q = 0; q < 4; ++q) {
      const int col = cl + 64*q;
      w0[q] = Wg[(j0+0)*kH + col];
      w1[q] = Wg[(j0+1)*kH + col];
      w2[q] = Wg[(j0+2)*kH + col];
      w3[q] = Wg[(j0+3)*kH + col];
    }
#pragma unroll
    for (int i = 0; i < 8; ++i)
#pragma unroll
      for (int q = 0; q < 4; ++q) {
        acc[i][q] = fmaf(c[i].x, w0[q], acc[i][q]);
        acc[i][q] = fmaf(c[i].y, w1[q], acc[i][q]);
        acc[i][q] = fmaf(c[i].z, w2[q], acc[i][q]);
        acc[i][q] = fmaf(c[i].w, w3[q], acc[i][q]);
      }
  }
#pragma unroll
  for (int i = 0; i < 8; ++i) {
    const size_t row = (size_t)(r0 + rg*8 + i);
#pragma unroll
    for (int q = 0; q < 4; ++q) h[row*kH + cl + 64*q] = acc[i][q];
  }
}

// ---- K1b: ha1 = h@a1, ha2 = h@a2 (one wave per row) ---------------------
__global__ __launch_bounds__(256) void k1b_ha(
    const float* __restrict__ h, const float* __restrict__ a_w,
    float* __restrict__ ha1, float* __restrict__ ha2)
{
  const int wid = threadIdx.x >> 6, lane = threadIdx.x & 63;
  const int row = blockIdx.x * 4 + wid;
  float s1 = 0.f, s2 = 0.f;
#pragma unroll
  for (int q = 0; q < 4; ++q) {
    const int k = lane + 64*q;
    const float hv = h[(size_t)row * kH + k];
    s1 = fmaf(hv, a_w[k], s1);
    s2 = fmaf(hv, a_w[kH + k], s2);
  }
#pragma unroll
  for (int off = 32; off; off >>= 1) {
    s1 += __shfl_down(s1, off);
    s2 += __shfl_down(s2, off);
  }
  if (lane == 0) { ha1[row] = s1; ha2[row] = s2; }
}

// ---- K2a: per-row softmax max + reciprocal denom (one wave per row) -----
__global__ __launch_bounds__(256) void k2a_stats(
    const float* __restrict__ ha1, const float* __restrict__ ha2,
    float* __restrict__ mOut, float* __restrict__ rdOut)
{
  const int wid = threadIdx.x >> 6, lane = threadIdx.x & 63;
  const int g = blockIdx.x * 4 + wid;   // global row (n*V + i)
  const int n = g >> 8;
  const float a = ha1[g];
  float e[4];
#pragma unroll
  for (int q = 0; q < 4; ++q) {
    float x = a + ha2[n*kV + lane + 64*q];
    e[q] = x > 0.f ? x : 0.01f * x;     // leaky_relu
  }
  float m = fmaxf(fmaxf(e[0], e[1]), fmaxf(e[2], e[3]));
#pragma unroll
  for (int off = 32; off; off >>= 1) m = fmaxf(m, __shfl_xor(m, off));
  float s = 0.f;
#pragma unroll
  for (int q = 0; q < 4; ++q) s += expf(e[q] - m);
#pragma unroll
  for (int off = 32; off; off >>= 1) s += __shfl_xor(s, off);
  if (lane == 0) { mOut[g] = m; rdOut[g] = 1.f / s; }
}

// ---- K2b: h_prime = att @ h (att regenerated into LDS) ------------------
__global__ __launch_bounds__(256) void k2b_attn(
    const float* __restrict__ ha1, const float* __restrict__ ha2,
    const float* __restrict__ mIn, const float* __restrict__ rdIn,
    const float* __restrict__ h, float* __restrict__ hp)
{
  __shared__ float att[32][kV];   // 32 KB
  const int t = threadIdx.x;
  const int tt = blockIdx.x;
  const int n = tt >> 3, i0 = (tt & 7) * 32;
  const float h2v = ha2[n*kV + t];
  for (int r = 0; r < 32; ++r) {
    const int g = n*kV + i0 + r;
    float x = ha1[g] + h2v;
    x = x > 0.f ? x : 0.01f * x;
    att[r][t] = expf(x - mIn[g]) * rdIn[g];
  }
  __syncthreads();

  const int rg = t >> 6, cl = t & 63;
  float acc[8][4];
#pragma unroll
  for (int i = 0; i < 8; ++i)
#pragma unroll
    for (int q = 0; q < 4; ++q) acc[i][q] = 0.f;

  for (int j0 = 0; j0 < kV; j0 += 4) {
    float4 c[8];
#pragma unroll
    for (int i = 0; i < 8; ++i)
      c[i] = *reinterpret_cast<const float4*>(&att[rg*8 + i][j0]);
    float w0[4], w1[4], w2[4], w3[4];
#pragma unroll
    for (int q = 0; q < 4; ++q) {
      const int col = cl + 64*q;
      w0[q] = h[((size_t)n*kV + j0+0)*kH + col];
      w1[q] = h[((size_t)n*kV + j0+1)*kH + col];
      w2[q] = h[((size_t)n*kV + j0+2)*kH + col];
      w3[q] = h[((size_t)n*kV + j0+3)*kH + col];
    }
#pragma unroll
    for (int i = 0; i < 8; ++i)
#pragma unroll
      for (int q = 0; q < 4; ++q) {
        acc[i][q] = fmaf(c[i].x, w0[q], acc[i][q]);
        acc[i][q] = fmaf(c[i].y, w1[q], acc[i][q]);
        acc[i][q] = fmaf(c[i].z, w2[q], acc[i][q]);
        acc[i][q] = fmaf(c[i].w, w3[q], acc[i][q]);
      }
  }
#pragma unroll
  for (int i = 0; i < 8; ++i) {
    const size_t row = (size_t)n*kV + i0 + rg*8 + i;
#pragma unroll
    for (int q = 0; q < 4; ++q) hp[row*kH + cl + 64*q] = acc[i][q];
  }
}

// ---- K3: y = [h_prime | se] @ W1 (+ BN1 stat partials) -------------------
// b1 omitted: a constant column shift cancels exactly in batchnorm.
__global__ __launch_bounds__(256) void k3_y(
    const float* __restrict__ hp, const float* __restrict__ obs,
    const float* __restrict__ Ws, const float* __restrict__ bs,
    const float* __restrict__ W1, float* __restrict__ y,
    float* __restrict__ st)
{
  __shared__ float cf[32][kH2];   // 64 KB
  const int t = threadIdx.x;
  const int r0 = blockIdx.x * 32;
  const float ws0 = Ws[t], ws1 = Ws[kH + t], bsv = bs[t];
  for (int r = 0; r < 32; ++r) {
    const int row = r0 + r;
    cf[r][t] = hp[(size_t)row*kH + t];
    const float o1 = obs[row*5+1], o2 = obs[row*5+2];
    float s = fmaf(o2, ws1, fmaf(o1, ws0, bsv));
    cf[r][kH + t] = s > 0.f ? s : 0.f;   // se recomputed (cheap)
  }
  __syncthreads();

  const int rg = t >> 6, cl = t & 63;
  float acc[8][4];
#pragma unroll
  for (int i = 0; i < 8; ++i)
#pragma unroll
    for (int q = 0; q < 4; ++q) acc[i][q] = 0.f;

  for (int j0 = 0; j0 < kH2; j0 += 4) {
    float4 c[8];
#pragma unroll
    for (int i = 0; i < 8; ++i)
      c[i] = *reinterpret_cast<const float4*>(&cf[rg*8 + i][j0]);
    float w0[4], w1[4], w2[4], w3[4];
#pragma unroll
    for (int q = 0; q < 4; ++q) {
      const int col = cl + 64*q;
      w0[q] = W1[(j0+0)*kH + col];
      w1[q] = W1[(j0+1)*kH + col];
      w2[q] = W1[(j0+2)*kH + col];
      w3[q] = W1[(j0+3)*kH + col];
    }
#pragma unroll
    for (int i = 0; i < 8; ++i)
#pragma unroll
      for (int q = 0; q < 4; ++q) {
        acc[i][q] = fmaf(c[i].x, w0[q], acc[i][q]);
        acc[i][q] = fmaf(c[i].y, w1[q], acc[i][q]);
        acc[i][q] = fmaf(c[i].z, w2[q], acc[i][q]);
        acc[i][q] = fmaf(c[i].w, w3[q], acc[i][q]);
      }
  }

  float s[4], ss[4];
#pragma unroll
  for (int q = 0; q < 4; ++q) { s[q] = 0.f; ss[q] = 0.f; }
#pragma unroll
  for (int i = 0; i < 8; ++i) {
    const size_t row = (size_t)(r0 + rg*8 + i);
#pragma unroll
    for (int q = 0; q < 4; ++q) {
      const float v = acc[i][q];
      y[row*kH + cl + 64*q] = v;
      s[q] += v; ss[q] += v * v;
    }
  }
  __syncthreads();               // done reading cf -> reuse as reduction buf
  float* red = &cf[0][0];        // 2048 floats used
#pragma unroll
  for (int q = 0; q < 4; ++q) {
    const int col = cl + 64*q;
    red[rg*256 + col] = s[q];
    red[1024 + rg*256 + col] = ss[q];
  }
  __syncthreads();
  if (rg == 0) {
#pragma unroll
    for (int q = 0; q < 4; ++q) {
      const int col = cl + 64*q;
      const float S  = red[col] + red[256+col] + red[512+col] + red[768+col];
      const float SS = red[1024+col] + red[1280+col] + red[1536+col] + red[1792+col];
      atomicAdd(&st[col], S);
      atomicAdd(&st[256 + col], SS);
    }
  }
}

// ---- K4: finalize BN1 -> scale1/shift1 -----------------------------------
__global__ __launch_bounds__(256) void k4_fin1(
    const float* __restrict__ g1, const float* __restrict__ be1, float* __restrict__ st)
{
  const int t = threadIdx.x;
  const float mean = st[t] * (1.f / kNV);
  const float var  = st[256 + t] * (1.f / kNV) - mean * mean;
  const float sc   = g1[t] / sqrtf(var + kEps);
  st[512 + t] = sc;
  st[768 + t] = be1[t] - mean * sc;
}

// ---- K5: z = relu(bn1(y)) @ W2 (+ BN2 stat partials) ----------------------
__global__ __launch_bounds__(256) void k5_z(
    const float* __restrict__ y, const float* __restrict__ W2,
    float* __restrict__ st, float* __restrict__ z)
{
  __shared__ float xs[32][kH];   // 32 KB
  const int t = threadIdx.x;
  const int r0 = blockIdx.x * 32;
  const float sc = st[512 + t], sh = st[768 + t];
  for (int r = 0; r < 32; ++r) {
    const float v = fmaf(y[(size_t)(r0 + r)*kH + t], sc, sh);
    xs[r][t] = v > 0.f ? v : 0.f;
  }
  __syncthreads();

  const int rg = t >> 6, cl = t & 63;
  float acc[8][2];
#pragma unroll
  for (int i = 0; i < 8; ++i) { acc[i][0] = 0.f; acc[i][1] = 0.f; }

  for (int j0 = 0; j0 < kH; j0 += 4) {
    float4 c[8];
#pragma unroll
    for (int i = 0; i < 8; ++i)
      c[i] = *reinterpret_cast<const float4*>(&xs[rg*8 + i][j0]);
    float w0[2], w1[2], w2[2], w3[2];
#pragma unroll
    for (int q = 0; q < 2; ++q) {
      const int col = cl + 64*q;
      w0[q] = W2[(j0+0)*kOut + col];
      w1[q] = W2[(j0+1)*kOut + col];
      w2[q] = W2[(j0+2)*kOut + col];
      w3[q] = W2[(j0+3)*kOut + col];
    }
#pragma unroll
    for (int i = 0; i < 8; ++i)
#pragma unroll
      for (int q = 0; q < 2; ++q) {
        acc[i][q] = fmaf(c[i].x, w0[q], acc[i][q]);
        acc[i][q] = fmaf(c[i].y, w1[q], acc[i][q]);
        acc[i][q] = fmaf(c[i].z, w2[q], acc[i][q]);
        acc[i][q] = fmaf(c[i].w, w3[q], acc[i][q]);
      }
  }

  float s[2] = {0.f, 0.f}, ss[2] = {0.f, 0.f};
#pragma unroll
  for (int i = 0; i < 8; ++i) {
    const size_t row = (size_t)(r0 + rg*8 + i);
#pragma unroll
    for (int q = 0; q < 2; ++q) {
      const float v = acc[i][q];
      z[row*kOut + cl + 64*q] = v;
      s[q] += v; ss[q] += v * v;
    }
  }
  __syncthreads();
  float* red = &xs[0][0];        // 1024 floats used
#pragma unroll
  for (int q = 0; q < 2; ++q) {
    const int col = cl + 64*q;
    red[rg*128 + col] = s[q];
    red[512 + rg*128 + col] = ss[q];
  }
  __syncthreads();
  if (rg == 0) {
#pragma unroll
    for (int q = 0; q < 2; ++q) {
      const int col = cl + 64*q;
      const float S  = red[col] + red[128+col] + red[256+col] + red[384+col];
      const float SS = red[512+col] + red[640+col] + red[768+col] + red[896+col];
      atomicAdd(&st[1024 + col], S);
      atomicAdd(&st[1152 + col], SS);
    }
  }
}

// ---- K6: finalize BN2 -----------------------------------------------------
__global__ __launch_bounds__(128) void k6_fin2(
    const float* __restrict__ g2, const float* __restrict__ be2, float* __restrict__ st)
{
  const int t = threadIdx.x;
  const float mean = st[1024 + t] * (1.f / kNV);
  const float var  = st[1152 + t] * (1.f / kNV) - mean * mean;
  const float sc   = g2[t] / sqrtf(var + kEps);
  st[1280 + t] = sc;
  st[1408 + t] = be2[t] - mean * sc;
}

// ---- K7: out = relu(bn2(z)) in-place on d_out -----------------------------
__global__ __launch_bounds__(256) void k7_out(float* __restrict__ z, const float* __restrict__ st)
{
  const size_t idx = (size_t)blockIdx.x * 256 + threadIdx.x;   // float4 index
  float4 v = reinterpret_cast<float4*>(z)[idx];
  const int col = (int)((idx * 4) & (kOut - 1));
  const float4 sc = *reinterpret_cast<const float4*>(&st[1280 + col]);
  const float4 sh = *reinterpret_cast<const float4*>(&st[1408 + col]);
  v.x = fmaxf(fmaf(v.x, sc.x, sh.x), 0.f);
  v.y = fmaxf(fmaf(v.y, sc.y, sh.y), 0.f);
  v.z = fmaxf(fmaf(v.z, sc.z, sh.z), 0.f);
  v.w = fmaxf(fmaf(v.w, sc.w, sh.w), 0.f);
  reinterpret_cast<float4*>(z)[idx] = v;
}

} // namespace

extern "C" void kernel_launch(void* const* d_in, const int* in_sizes, int n_in,
                              void* d_out, int out_size, void* d_ws, size_t ws_size,
                              hipStream_t stream) {
  const float* obs = (const float*)d_in[0];
  const float* hi  = (const float*)d_in[1];
  const float* Ws  = (const float*)d_in[2];
  const float* bs  = (const float*)d_in[3];
  const float* Wv  = (const float*)d_in[4];
  const float* bv  = (const float*)d_in[5];
  const float* Wg  = (const float*)d_in[6];
  const float* a_w = (const float*)d_in[7];
  const float* W1  = (const float*)d_in[8];
  // d_in[9] = b1: unused (cancels in batchnorm)
  const float* g1  = (const float*)d_in[10];
  const float* be1 = (const float*)d_in[11];
  const float* W2  = (const float*)d_in[12];
  // d_in[13] = b2: unused (cancels in batchnorm)
  const float* g2  = (const float*)d_in[14];
  const float* be2 = (const float*)d_in[15];

  float* ws  = (float*)d_ws;
  float* h   = ws + offH;
  float* hp  = ws + offHP;
  float* ha1 = ws + offHA1;
  float* ha2 = ws + offHA2;
  float* m   = ws + offM;
  float* rd  = ws + offRD;
  float* st  = ws + offST;
  float* y   = ws + offH;        // reuse h region after attention
  float* z   = (float*)d_out;

  k0_zero <<<1,            256, 0, stream>>>(st);
  k1_encode<<<kNV / 32,    256, 0, stream>>>(obs, hi, Ws, bs, Wv, bv, Wg, h);
  k1b_ha  <<<kNV / 4,      256, 0, stream>>>(h, a_w, ha1, ha2);
  k2a_stats<<<kNV / 4,     256, 0, stream>>>(ha1, ha2, m, rd);
  k2b_attn<<<kNV / 32,     256, 0, stream>>>(ha1, ha2, m, rd, h, hp);
  k3_y    <<<kNV / 32,     256, 0, stream>>>(hp, obs, Ws, bs, W1, y, st);
  k4_fin1 <<<1,            256, 0, stream>>>(g1, be1, st);
  k5_z    <<<kNV / 32,     256, 0, stream>>>(y, W2, st, z);
  k6_fin2 <<<1,            128, 0, stream>>>(g2, be2, st);
  k7_out  <<<(kNV * kOut / 4) / 256, 256, 0, stream>>>(z, st);
}

// Round 2
// 221.657 us; speedup vs baseline: 3.3773x; 3.3773x over previous
//
#include <hip/hip_runtime.h>
#include <math.h>

namespace {

constexpr int kH = 256, kLat = 64, kOut = 128;
constexpr int kGin = 576, kH2 = 512, kNV = 65536;
constexpr float kEps = 1e-5f;

typedef __attribute__((ext_vector_type(8))) short bf16x8;
typedef __attribute__((ext_vector_type(4))) float f32x4;
typedef unsigned int u32;

__device__ inline short f2bf(float f) {
  union { float f; u32 u; } v; v.f = f;
  u32 r = v.u + 0x7fffu + ((v.u >> 16) & 1u);
  return (short)(r >> 16);
}
__device__ inline float bf2f(short s) {
  union { float f; u32 u; } v; v.u = ((u32)(unsigned short)s) << 16; return v.f;
}

// ---- K0: zero the stats block --------------------------------------------
__global__ __launch_bounds__(256) void k0_zero(float* __restrict__ st) {
  const int t = threadIdx.x;
  st[t] = 0.f;          // sum1
  st[256 + t] = 0.f;    // sumsq1
  st[1024 + t] = 0.f;   // sum2 + sumsq2
}

// ---- KP: pack Wg/W1/W2 into MFMA B-fragment order (bf16) -----------------
// unit (kt, ct, lane) holds 8 bf16: W[kt*32 + (lane>>4)*8 + e][ct*16 + (lane&15)]
__global__ __launch_bounds__(256) void kpack(
    const float* __restrict__ Wg, const float* __restrict__ W1,
    const float* __restrict__ W2,
    short* __restrict__ wgp, short* __restrict__ w1p, short* __restrict__ w2p)
{
  const int uid = blockIdx.x * 256 + threadIdx.x;
  const float* src; short* dst; int N; int u;
  if (uid < 18432)            { src = Wg; dst = wgp; N = 256; u = uid; }
  else if (uid < 34816)       { src = W1; dst = w1p; N = 256; u = uid - 18432; }
  else if (uid < 38912)       { src = W2; dst = w2p; N = 128; u = uid - 34816; }
  else return;
  const int lane = u & 63, ctkt = u >> 6;
  const int nct = N >> 4;
  const int kt = ctkt / nct, ct = ctkt % nct;
  const int row = kt * 32 + (lane >> 4) * 8;
  const int col = ct * 16 + (lane & 15);
  bf16x8 ov;
#pragma unroll
  for (int e = 0; e < 8; ++e) ov[e] = f2bf(src[(size_t)(row + e) * N + col]);
  *reinterpret_cast<bf16x8*>(dst + (size_t)u * 8) = ov;
}

// ---- K1: comb = [se|ve|hi] (LDS bf16), h = comb @ Wg (MFMA),
//          epilogue: ha1/ha2 from fp32 acc + h scattered into packed-B layout
__global__ __launch_bounds__(256) void k1_encode(
    const float* __restrict__ obs, const float* __restrict__ hi,
    const float* __restrict__ Ws, const float* __restrict__ bs,
    const float* __restrict__ Wv, const float* __restrict__ bv,
    const short* __restrict__ wgp, const float* __restrict__ a_w,
    short* __restrict__ hpack, float* __restrict__ ha1, float* __restrict__ ha2)
{
  __shared__ __align__(16) short comb[64][584];   // 74752 B, stride 1168B (73*16)
  __shared__ float red1[4][64];
  __shared__ float red2[4][64];
  const int t = threadIdx.x;
  const int r0 = blockIdx.x * 64;
  const float ws0 = Ws[t], ws1 = Ws[kH + t], bsv = bs[t];
  const float wv0 = Wv[t], wv1 = Wv[kH + t], bvv = bv[t];
  for (int r = 0; r < 64; ++r) {
    const int row = r0 + r;
    const float o1 = obs[row*5+1], o2 = obs[row*5+2];
    const float o3 = obs[row*5+3], o4 = obs[row*5+4];
    float s = fmaf(o2, ws1, fmaf(o1, ws0, bsv));
    comb[r][t] = f2bf(s > 0.f ? s : 0.f);
    float v = fmaf(o4, wv1, fmaf(o3, wv0, bvv));
    comb[r][kH + t] = f2bf(v > 0.f ? v : 0.f);
    if (t < kLat) comb[r][2*kH + t] = f2bf(hi[(size_t)row * kLat + t]);
  }
  __syncthreads();

  const int w = t >> 6, lane = t & 63, lo = lane & 15, hi4 = lane >> 4;
  f32x4 acc[4][4];
#pragma unroll
  for (int rt = 0; rt < 4; ++rt)
#pragma unroll
    for (int ct = 0; ct < 4; ++ct) acc[rt][ct] = (f32x4){0.f, 0.f, 0.f, 0.f};

  for (int ks = 0; ks < 18; ++ks) {
    bf16x8 a[4];
#pragma unroll
    for (int rt = 0; rt < 4; ++rt)
      a[rt] = *reinterpret_cast<const bf16x8*>(&comb[rt*16 + lo][ks*32 + hi4*8]);
    bf16x8 b[4];
#pragma unroll
    for (int ct = 0; ct < 4; ++ct)
      b[ct] = *reinterpret_cast<const bf16x8*>(wgp + ((size_t)(ks*16 + w*4 + ct)*64 + lane)*8);
#pragma unroll
    for (int rt = 0; rt < 4; ++rt)
#pragma unroll
      for (int ct = 0; ct < 4; ++ct)
        acc[rt][ct] = __builtin_amdgcn_mfma_f32_16x16x32_bf16(a[rt], b[ct], acc[rt][ct], 0, 0, 0);
  }

  // ha partials from fp32 acc: ha[row] = sum_col h[row][col] * a[col]
  float a1v[4], a2v[4];
#pragma unroll
  for (int ct = 0; ct < 4; ++ct) {
    const int col = w*64 + ct*16 + lo;
    a1v[ct] = a_w[col]; a2v[ct] = a_w[kH + col];
  }
#pragma unroll
  for (int rt = 0; rt < 4; ++rt)
#pragma unroll
    for (int q = 0; q < 4; ++q) {
      float p1 = 0.f, p2 = 0.f;
#pragma unroll
      for (int ct = 0; ct < 4; ++ct) {
        p1 = fmaf(acc[rt][ct][q], a1v[ct], p1);
        p2 = fmaf(acc[rt][ct][q], a2v[ct], p2);
      }
#pragma unroll
      for (int off = 1; off < 16; off <<= 1) {
        p1 += __shfl_xor(p1, off);
        p2 += __shfl_xor(p2, off);
      }
      if (lo == 0) {
        const int rl = rt*16 + hi4*4 + q;
        red1[w][rl] = p1; red2[w][rl] = p2;
      }
    }

  // scatter h into packed-B layout: unit(n,kt,ct,lane')*8 + e
  const int n = r0 >> 8;
  const int j0 = r0 & 255;
#pragma unroll
  for (int rt = 0; rt < 4; ++rt)
#pragma unroll
    for (int q = 0; q < 4; ++q) {
      const int j = j0 + rt*16 + hi4*4 + q;
      const int kt = j >> 5, khi = (j >> 3) & 3, e = j & 7;
#pragma unroll
      for (int ct = 0; ct < 4; ++ct) {
        const size_t unit = ((size_t)(n*8 + kt)*16 + (w*4 + ct))*64 + khi*16 + lo;
        hpack[unit*8 + e] = f2bf(acc[rt][ct][q]);
      }
    }
  __syncthreads();
  if (t < 64) {
    ha1[r0 + t] = red1[0][t] + red1[1][t] + red1[2][t] + red1[3][t];
  } else if (t < 128) {
    const int tt = t - 64;
    ha2[r0 + tt] = red2[0][tt] + red2[1][tt] + red2[2][tt] + red2[3][tt];
  }
}

// ---- K2a: per-row softmax max + reciprocal denom (one wave per row) ------
__global__ __launch_bounds__(256) void k2a_stats(
    const float* __restrict__ ha1, const float* __restrict__ ha2,
    float* __restrict__ mOut, float* __restrict__ rdOut)
{
  const int wid = threadIdx.x >> 6, lane = threadIdx.x & 63;
  const int g = blockIdx.x * 4 + wid;
  const int n = g >> 8;
  const float a = ha1[g];
  float e[4];
#pragma unroll
  for (int q = 0; q < 4; ++q) {
    float x = a + ha2[n*256 + lane + 64*q];
    e[q] = x > 0.f ? x : 0.01f * x;
  }
  float m = fmaxf(fmaxf(e[0], e[1]), fmaxf(e[2], e[3]));
#pragma unroll
  for (int off = 32; off; off >>= 1) m = fmaxf(m, __shfl_xor(m, off));
  float s = 0.f;
#pragma unroll
  for (int q = 0; q < 4; ++q) s += __expf(e[q] - m);
#pragma unroll
  for (int off = 32; off; off >>= 1) s += __shfl_xor(s, off);
  if (lane == 0) { mOut[g] = m; rdOut[g] = 1.f / s; }
}

// ---- K2b: hp = att @ h, att generated into LDS bf16, B = packed h --------
__global__ __launch_bounds__(256) void k2b_attn(
    const float* __restrict__ ha1, const float* __restrict__ ha2,
    const float* __restrict__ mIn, const float* __restrict__ rdIn,
    const short* __restrict__ hpack, short* __restrict__ hp)
{
  __shared__ __align__(16) short att[64][264];   // 33792 B
  const int t = threadIdx.x;
  const int r0 = blockIdx.x * 64;
  const int n = r0 >> 8;
  const float h2v = ha2[n*256 + t];
  for (int r = 0; r < 64; ++r) {
    const int g = r0 + r;
    float x = ha1[g] + h2v;
    x = x > 0.f ? x : 0.01f * x;
    att[r][t] = f2bf(__expf(x - mIn[g]) * rdIn[g]);
  }
  __syncthreads();

  const int w = t >> 6, lane = t & 63, lo = lane & 15, hi4 = lane >> 4;
  f32x4 acc[4][4];
#pragma unroll
  for (int rt = 0; rt < 4; ++rt)
#pragma unroll
    for (int ct = 0; ct < 4; ++ct) acc[rt][ct] = (f32x4){0.f, 0.f, 0.f, 0.f};

  for (int ks = 0; ks < 8; ++ks) {
    bf16x8 a[4];
#pragma unroll
    for (int rt = 0; rt < 4; ++rt)
      a[rt] = *reinterpret_cast<const bf16x8*>(&att[rt*16 + lo][ks*32 + hi4*8]);
    bf16x8 b[4];
#pragma unroll
    for (int ct = 0; ct < 4; ++ct)
      b[ct] = *reinterpret_cast<const bf16x8*>(hpack + ((size_t)((n*8 + ks)*16 + w*4 + ct)*64 + lane)*8);
#pragma unroll
    for (int rt = 0; rt < 4; ++rt)
#pragma unroll
      for (int ct = 0; ct < 4; ++ct)
        acc[rt][ct] = __builtin_amdgcn_mfma_f32_16x16x32_bf16(a[rt], b[ct], acc[rt][ct], 0, 0, 0);
  }
#pragma unroll
  for (int rt = 0; rt < 4; ++rt)
#pragma unroll
    for (int q = 0; q < 4; ++q) {
      const size_t row = (size_t)r0 + rt*16 + hi4*4 + q;
#pragma unroll
      for (int ct = 0; ct < 4; ++ct)
        hp[row*kH + w*64 + ct*16 + lo] = f2bf(acc[rt][ct][q]);
    }
}

// ---- K3: y = [hp|se] @ W1 (bf16 MFMA) + BN1 stat atomics ------------------
__global__ __launch_bounds__(256) void k3_y(
    const short* __restrict__ hp, const float* __restrict__ obs,
    const float* __restrict__ Ws, const float* __restrict__ bs,
    const short* __restrict__ w1p, short* __restrict__ y, float* __restrict__ st)
{
  __shared__ __align__(16) short cf[64][520];   // 66560 B, stride 1040B (65*16)
  const int t = threadIdx.x;
  const int r0 = blockIdx.x * 64;
#pragma unroll
  for (int it = 0; it < 8; ++it) {
    const int u = t + 256*it, row = u >> 5, seg = u & 31;
    bf16x8 v = *reinterpret_cast<const bf16x8*>(hp + (size_t)(r0 + row)*kH + seg*8);
    *reinterpret_cast<bf16x8*>(&cf[row][seg*8]) = v;
  }
  const float ws0 = Ws[t], ws1 = Ws[kH + t], bsv = bs[t];
  for (int r = 0; r < 64; ++r) {
    const int row = r0 + r;
    const float o1 = obs[row*5+1], o2 = obs[row*5+2];
    float s = fmaf(o2, ws1, fmaf(o1, ws0, bsv));
    cf[r][kH + t] = f2bf(s > 0.f ? s : 0.f);
  }
  __syncthreads();

  const int w = t >> 6, lane = t & 63, lo = lane & 15, hi4 = lane >> 4;
  f32x4 acc[4][4];
#pragma unroll
  for (int rt = 0; rt < 4; ++rt)
#pragma unroll
    for (int ct = 0; ct < 4; ++ct) acc[rt][ct] = (f32x4){0.f, 0.f, 0.f, 0.f};

  for (int ks = 0; ks < 16; ++ks) {
    bf16x8 a[4];
#pragma unroll
    for (int rt = 0; rt < 4; ++rt)
      a[rt] = *reinterpret_cast<const bf16x8*>(&cf[rt*16 + lo][ks*32 + hi4*8]);
    bf16x8 b[4];
#pragma unroll
    for (int ct = 0; ct < 4; ++ct)
      b[ct] = *reinterpret_cast<const bf16x8*>(w1p + ((size_t)(ks*16 + w*4 + ct)*64 + lane)*8);
#pragma unroll
    for (int rt = 0; rt < 4; ++rt)
#pragma unroll
      for (int ct = 0; ct < 4; ++ct)
        acc[rt][ct] = __builtin_amdgcn_mfma_f32_16x16x32_bf16(a[rt], b[ct], acc[rt][ct], 0, 0, 0);
  }

  float s[4] = {0,0,0,0}, ss[4] = {0,0,0,0};
#pragma unroll
  for (int rt = 0; rt < 4; ++rt)
#pragma unroll
    for (int q = 0; q < 4; ++q) {
      const size_t row = (size_t)r0 + rt*16 + hi4*4 + q;
#pragma unroll
      for (int ct = 0; ct < 4; ++ct) {
        const float v = acc[rt][ct][q];
        y[row*kH + w*64 + ct*16 + lo] = f2bf(v);
        s[ct] += v; ss[ct] += v * v;
      }
    }
#pragma unroll
  for (int off = 16; off < 64; off <<= 1)
#pragma unroll
    for (int ct = 0; ct < 4; ++ct) {
      s[ct] += __shfl_xor(s[ct], off);
      ss[ct] += __shfl_xor(ss[ct], off);
    }
  if (hi4 == 0)
#pragma unroll
    for (int ct = 0; ct < 4; ++ct) {
      const int col = w*64 + ct*16 + lo;
      atomicAdd(&st[col], s[ct]);
      atomicAdd(&st[256 + col], ss[ct]);
    }
}

// ---- K4: finalize BN1 ------------------------------------------------------
__global__ __launch_bounds__(256) void k4_fin1(
    const float* __restrict__ g1, const float* __restrict__ be1, float* __restrict__ st)
{
  const int t = threadIdx.x;
  const float mean = st[t] * (1.f / kNV);
  const float var  = st[256 + t] * (1.f / kNV) - mean * mean;
  const float sc   = g1[t] / sqrtf(var + kEps);
  st[512 + t] = sc;
  st[768 + t] = be1[t] - mean * sc;
}

// ---- K5: z = relu(bn1(y)) @ W2 (bf16 MFMA) + BN2 stat atomics --------------
__global__ __launch_bounds__(256) void k5_z(
    const short* __restrict__ y, const short* __restrict__ w2p,
    float* __restrict__ st, float* __restrict__ z)
{
  __shared__ __align__(16) short xs[64][264];   // 33792 B
  const int t = threadIdx.x;
  const int r0 = blockIdx.x * 64;
#pragma unroll
  for (int it = 0; it < 8; ++it) {
    const int u = t + 256*it, row = u >> 5, seg = u & 31;
    bf16x8 v = *reinterpret_cast<const bf16x8*>(y + (size_t)(r0 + row)*kH + seg*8);
    bf16x8 ov;
#pragma unroll
    for (int e = 0; e < 8; ++e) {
      const int col = seg*8 + e;
      const float f = fmaf(bf2f(v[e]), st[512 + col], st[768 + col]);
      ov[e] = f2bf(f > 0.f ? f : 0.f);
    }
    *reinterpret_cast<bf16x8*>(&xs[row][seg*8]) = ov;
  }
  __syncthreads();

  const int w = t >> 6, lane = t & 63, lo = lane & 15, hi4 = lane >> 4;
  f32x4 acc[4][2];
#pragma unroll
  for (int rt = 0; rt < 4; ++rt)
#pragma unroll
    for (int ct = 0; ct < 2; ++ct) acc[rt][ct] = (f32x4){0.f, 0.f, 0.f, 0.f};

  for (int ks = 0; ks < 8; ++ks) {
    bf16x8 a[4];
#pragma unroll
    for (int rt = 0; rt < 4; ++rt)
      a[rt] = *reinterpret_cast<const bf16x8*>(&xs[rt*16 + lo][ks*32 + hi4*8]);
    bf16x8 b[2];
#pragma unroll
    for (int ct = 0; ct < 2; ++ct)
      b[ct] = *reinterpret_cast<const bf16x8*>(w2p + ((size_t)(ks*8 + w*2 + ct)*64 + lane)*8);
#pragma unroll
    for (int rt = 0; rt < 4; ++rt)
#pragma unroll
      for (int ct = 0; ct < 2; ++ct)
        acc[rt][ct] = __builtin_amdgcn_mfma_f32_16x16x32_bf16(a[rt], b[ct], acc[rt][ct], 0, 0, 0);
  }

  float s[2] = {0,0}, ss[2] = {0,0};
#pragma unroll
  for (int rt = 0; rt < 4; ++rt)
#pragma unroll
    for (int q = 0; q < 4; ++q) {
      const size_t row = (size_t)r0 + rt*16 + hi4*4 + q;
#pragma unroll
      for (int ct = 0; ct < 2; ++ct) {
        const float v = acc[rt][ct][q];
        z[row*kOut + w*32 + ct*16 + lo] = v;
        s[ct] += v; ss[ct] += v * v;
      }
    }
#pragma unroll
  for (int off = 16; off < 64; off <<= 1)
#pragma unroll
    for (int ct = 0; ct < 2; ++ct) {
      s[ct] += __shfl_xor(s[ct], off);
      ss[ct] += __shfl_xor(ss[ct], off);
    }
  if (hi4 == 0)
#pragma unroll
    for (int ct = 0; ct < 2; ++ct) {
      const int col = w*32 + ct*16 + lo;
      atomicAdd(&st[1024 + col], s[ct]);
      atomicAdd(&st[1152 + col], ss[ct]);
    }
}

// ---- K6: finalize BN2 ------------------------------------------------------
__global__ __launch_bounds__(128) void k6_fin2(
    const float* __restrict__ g2, const float* __restrict__ be2, float* __restrict__ st)
{
  const int t = threadIdx.x;
  const float mean = st[1024 + t] * (1.f / kNV);
  const float var  = st[1152 + t] * (1.f / kNV) - mean * mean;
  const float sc   = g2[t] / sqrtf(var + kEps);
  st[1280 + t] = sc;
  st[1408 + t] = be2[t] - mean * sc;
}

// ---- K7: out = relu(bn2(z)) in-place on d_out ------------------------------
__global__ __launch_bounds__(256) void k7_out(float* __restrict__ z, const float* __restrict__ st)
{
  const size_t idx = (size_t)blockIdx.x * 256 + threadIdx.x;
  float4 v = reinterpret_cast<float4*>(z)[idx];
  const int col = (int)((idx * 4) & (kOut - 1));
  const float4 sc = *reinterpret_cast<const float4*>(&st[1280 + col]);
  const float4 sh = *reinterpret_cast<const float4*>(&st[1408 + col]);
  v.x = fmaxf(fmaf(v.x, sc.x, sh.x), 0.f);
  v.y = fmaxf(fmaf(v.y, sc.y, sh.y), 0.f);
  v.z = fmaxf(fmaf(v.z, sc.z, sh.z), 0.f);
  v.w = fmaxf(fmaf(v.w, sc.w, sh.w), 0.f);
  reinterpret_cast<float4*>(z)[idx] = v;
}

} // namespace

extern "C" void kernel_launch(void* const* d_in, const int* in_sizes, int n_in,
                              void* d_out, int out_size, void* d_ws, size_t ws_size,
                              hipStream_t stream) {
  const float* obs = (const float*)d_in[0];
  const float* hi  = (const float*)d_in[1];
  const float* Ws  = (const float*)d_in[2];
  const float* bs  = (const float*)d_in[3];
  const float* Wv  = (const float*)d_in[4];
  const float* bv  = (const float*)d_in[5];
  const float* Wg  = (const float*)d_in[6];
  const float* a_w = (const float*)d_in[7];
  const float* W1  = (const float*)d_in[8];
  // d_in[9] = b1: cancels in batchnorm
  const float* g1  = (const float*)d_in[10];
  const float* be1 = (const float*)d_in[11];
  const float* W2  = (const float*)d_in[12];
  // d_in[13] = b2: cancels in batchnorm
  const float* g2  = (const float*)d_in[14];
  const float* be2 = (const float*)d_in[15];

  char* base = (char*)d_ws;
  short* hpack = (short*)(base);                 // 33.5 MB; reused as y after k2b
  short* hp    = (short*)(base + 33554432);      // 33.5 MB
  float* ha1   = (float*)(base + 67108864);
  float* ha2   = (float*)(base + 67371008);
  float* m     = (float*)(base + 67633152);
  float* rd    = (float*)(base + 67895296);
  float* st    = (float*)(base + 68157440);      // 6144 B
  short* wgp   = (short*)(base + 68163584);      // 294912 B
  short* w1p   = (short*)(base + 68458496);      // 262144 B
  short* w2p   = (short*)(base + 68720640);      // 65536 B
  short* y     = hpack;
  float* z     = (float*)d_out;

  k0_zero  <<<1,     256, 0, stream>>>(st);
  kpack    <<<152,   256, 0, stream>>>(Wg, W1, W2, wgp, w1p, w2p);
  k1_encode<<<1024,  256, 0, stream>>>(obs, hi, Ws, bs, Wv, bv, wgp, a_w, hpack, ha1, ha2);
  k2a_stats<<<16384, 256, 0, stream>>>(ha1, ha2, m, rd);
  k2b_attn <<<1024,  256, 0, stream>>>(ha1, ha2, m, rd, hpack, hp);
  k3_y     <<<1024,  256, 0, stream>>>(hp, obs, Ws, bs, w1p, y, st);
  k4_fin1  <<<1,     256, 0, stream>>>(g1, be1, st);
  k5_z     <<<1024,  256, 0, stream>>>(y, w2p, st, z);
  k6_fin2  <<<1,     128, 0, stream>>>(g2, be2, st);
  k7_out   <<<8192,  256, 0, stream>>>(z, st);
}

// Round 4
// 155.230 us; speedup vs baseline: 4.8226x; 1.4279x over previous
//
#include <hip/hip_runtime.h>
#include <math.h>

namespace {

constexpr int kH = 256, kOut = 128;
constexpr int kNV = 65536;
constexpr float kEps = 1e-5f;

typedef __attribute__((ext_vector_type(8))) short bf16x8;
typedef __attribute__((ext_vector_type(4))) float f32x4;
typedef unsigned int u32;

__device__ inline short f2bf(float f) {
  union { float f; u32 u; } v; v.f = f;
  u32 r = v.u + 0x7fffu + ((v.u >> 16) & 1u);
  return (short)(r >> 16);
}
__device__ inline float bf2f(short s) {
  union { float f; u32 u; } v; v.u = ((u32)(unsigned short)s) << 16; return v.f;
}

// ---- KP: pack Wg/W1/W2 into MFMA B-fragment order (bf16); zero stats ------
// unit (kt, ct, lane) holds 8 bf16: W[kt*32 + (lane>>4)*8 + e][ct*16 + (lane&15)]
__global__ __launch_bounds__(256) void kpack(
    const float* __restrict__ Wg, const float* __restrict__ W1,
    const float* __restrict__ W2,
    short* __restrict__ wgp, short* __restrict__ w1p, short* __restrict__ w2p,
    float* __restrict__ st)
{
  if (blockIdx.x == 0) {
#pragma unroll
    for (int i = 0; i < 6; ++i) st[i*256 + threadIdx.x] = 0.f;
  }
  const int uid = blockIdx.x * 256 + threadIdx.x;
  const float* src; short* dst; int N; int u;
  if (uid < 18432)            { src = Wg; dst = wgp; N = 256; u = uid; }
  else if (uid < 34816)       { src = W1; dst = w1p; N = 256; u = uid - 18432; }
  else if (uid < 38912)       { src = W2; dst = w2p; N = 128; u = uid - 34816; }
  else return;
  const int lane = u & 63, ctkt = u >> 6;
  const int nct = N >> 4;
  const int kt = ctkt / nct, ct = ctkt % nct;
  const int row = kt * 32 + (lane >> 4) * 8;
  const int col = ct * 16 + (lane & 15);
  bf16x8 ov;
#pragma unroll
  for (int e = 0; e < 8; ++e) ov[e] = f2bf(src[(size_t)(row + e) * N + col]);
  *reinterpret_cast<bf16x8*>(dst + (size_t)u * 8) = ov;
}

// ---- K1: comb = [se|ve|hi] (LDS bf16), h = comb @ Wg (MFMA),
//          ha1/ha2 from fp32 acc; h emitted in packed-B layout via LDS tile
__global__ __launch_bounds__(256) void k1_encode(
    const float* __restrict__ obs, const float* __restrict__ hin,
    const float* __restrict__ Ws, const float* __restrict__ bs,
    const float* __restrict__ Wv, const float* __restrict__ bv,
    const short* __restrict__ wgp, const float* __restrict__ a_w,
    short* __restrict__ hpack, float* __restrict__ ha1, float* __restrict__ ha2)
{
  __shared__ __align__(16) short comb[64][584];   // 74752 B; reused as pack image
  __shared__ float red1[4][64], red2[4][64];
  __shared__ float obs_s[64][4];
  const int t = threadIdx.x;
  const int r0 = blockIdx.x * 64;

  // obs tile: one coalesced-ish load per thread
  {
    const int row = t >> 2, el = t & 3;
    obs_s[row][el] = obs[(size_t)(r0 + row) * 5 + 1 + el];
  }
  // hi tile: 4096 floats, coalesced float4, straight to comb cols 512..575
#pragma unroll
  for (int jj = 0; jj < 4; ++jj) {
    const int f = jj * 1024 + t * 4;
    const int row = f >> 6, c = f & 63;
    const float4 v = *reinterpret_cast<const float4*>(hin + (size_t)r0 * 64 + f);
    short4 o;
    o.x = f2bf(v.x); o.y = f2bf(v.y); o.z = f2bf(v.z); o.w = f2bf(v.w);
    *reinterpret_cast<short4*>(&comb[row][512 + c]) = o;
  }
  const float ws0 = Ws[t], ws1 = Ws[256 + t], bsv = bs[t];
  const float wv0 = Wv[t], wv1 = Wv[256 + t], bvv = bv[t];
  __syncthreads();
  // se/ve from LDS obs (no global latency in the loop)
  for (int r = 0; r < 64; ++r) {
    const float o1 = obs_s[r][0], o2 = obs_s[r][1], o3 = obs_s[r][2], o4 = obs_s[r][3];
    const float sv = fmaf(o2, ws1, fmaf(o1, ws0, bsv));
    comb[r][t] = f2bf(fmaxf(sv, 0.f));
    const float vv = fmaf(o4, wv1, fmaf(o3, wv0, bvv));
    comb[r][256 + t] = f2bf(fmaxf(vv, 0.f));
  }
  __syncthreads();

  const int w = t >> 6, lane = t & 63, lo = lane & 15, hq = lane >> 4;
  f32x4 acc[4][4];
#pragma unroll
  for (int rt = 0; rt < 4; ++rt)
#pragma unroll
    for (int ct = 0; ct < 4; ++ct) acc[rt][ct] = (f32x4){0.f, 0.f, 0.f, 0.f};

  for (int ks = 0; ks < 18; ++ks) {
    bf16x8 a[4];
#pragma unroll
    for (int rt = 0; rt < 4; ++rt)
      a[rt] = *reinterpret_cast<const bf16x8*>(&comb[rt*16 + lo][ks*32 + hq*8]);
    bf16x8 b[4];
#pragma unroll
    for (int ct = 0; ct < 4; ++ct)
      b[ct] = *reinterpret_cast<const bf16x8*>(wgp + ((size_t)(ks*16 + w*4 + ct)*64 + lane)*8);
#pragma unroll
    for (int rt = 0; rt < 4; ++rt)
#pragma unroll
      for (int ct = 0; ct < 4; ++ct)
        acc[rt][ct] = __builtin_amdgcn_mfma_f32_16x16x32_bf16(a[rt], b[ct], acc[rt][ct], 0, 0, 0);
  }

  // ha partials: ha[row] = sum_col h[row][col]*a_w[col]
  float a1v[4], a2v[4];
#pragma unroll
  for (int ct = 0; ct < 4; ++ct) {
    const int col = w*64 + ct*16 + lo;
    a1v[ct] = a_w[col]; a2v[ct] = a_w[kH + col];
  }
#pragma unroll
  for (int rt = 0; rt < 4; ++rt)
#pragma unroll
    for (int q = 0; q < 4; ++q) {
      float p1 = 0.f, p2 = 0.f;
#pragma unroll
      for (int ct = 0; ct < 4; ++ct) {
        p1 = fmaf(acc[rt][ct][q], a1v[ct], p1);
        p2 = fmaf(acc[rt][ct][q], a2v[ct], p2);
      }
#pragma unroll
      for (int off = 1; off < 16; off <<= 1) {
        p1 += __shfl_xor(p1, off);
        p2 += __shfl_xor(p2, off);
      }
      if (lo == 0) {
        const int rl = rt*16 + hq*4 + q;
        red1[w][rl] = p1; red2[w][rl] = p2;
      }
    }
  __syncthreads();   // comb reads + red writes complete

  // build 32 KB pack image in comb space
  short* pimg = reinterpret_cast<short*>(&comb[0][0]);
#pragma unroll
  for (int rt = 0; rt < 4; ++rt)
#pragma unroll
    for (int ct = 0; ct < 4; ++ct) {
      const int base = (((rt>>1)*16 + (w*4 + ct))*64 + ((rt&1)*2 + (hq>>1))*16 + lo)*8 + (hq&1)*4;
      short4 val;
      val.x = f2bf(acc[rt][ct][0]); val.y = f2bf(acc[rt][ct][1]);
      val.z = f2bf(acc[rt][ct][2]); val.w = f2bf(acc[rt][ct][3]);
      *reinterpret_cast<short4*>(pimg + base) = val;
    }
  if (t < 64) {
    ha1[r0 + t] = red1[0][t] + red1[1][t] + red1[2][t] + red1[3][t];
  } else if (t < 128) {
    const int tt = t - 64;
    ha2[r0 + tt] = red2[0][tt] + red2[1][tt] + red2[2][tt] + red2[3][tt];
  }
  __syncthreads();

  // contiguous 32 KB store
  const int n = r0 >> 8;
  short* dst = hpack + ((size_t)(n*8 + ((r0 & 255) >> 5))) * 8192;
#pragma unroll
  for (int j = 0; j < 8; ++j)
    *reinterpret_cast<bf16x8*>(dst + j*2048 + t*8) =
        *reinterpret_cast<const bf16x8*>(pimg + j*2048 + t*8);
}

// ---- K23: softmax stats + h' = att@h + y = [h'|se]@W1 + BN1 sums ----------
__global__ __launch_bounds__(256) void k23_attn_fc1(
    const float* __restrict__ ha1g, const float* __restrict__ ha2g,
    const short* __restrict__ hpack, const float* __restrict__ obs,
    const float* __restrict__ Ws, const float* __restrict__ bs,
    const short* __restrict__ w1p, short* __restrict__ y, float* __restrict__ st)
{
  __shared__ __align__(16) short attimg[64][264];  // att -> h' tile -> y tile
  __shared__ __align__(16) short se_s[64][264];
  __shared__ float ha2_s[256];
  __shared__ float ha1_s[64], m_s[64], rd_s[64];
  __shared__ float red[4][64];
  __shared__ float obs_s[64][2];
  const int t = threadIdx.x;
  const int r0 = blockIdx.x * 64;
  const int n = r0 >> 8;

  if (t < 128) {
    const int row = t >> 1, el = t & 1;
    obs_s[row][el] = obs[(size_t)(r0 + row) * 5 + 1 + el];
  }
  ha2_s[t] = ha2g[n*256 + t];
  if (t < 64) ha1_s[t] = ha1g[r0 + t];
  const float ws0 = Ws[t], ws1 = Ws[256 + t], bsv = bs[t];
  __syncthreads();

  // se tile (cols of FC1 input 256..511)
  for (int r = 0; r < 64; ++r) {
    const float sv = fmaf(obs_s[r][1], ws1, fmaf(obs_s[r][0], ws0, bsv));
    se_s[r][t] = f2bf(fmaxf(sv, 0.f));
  }

  // softmax stats: 4 threads per row, 64 cols each
  const int rr = t & 63, seg = t >> 6;
  const float a1 = ha1_s[rr];
  float mx = -3.0e38f;
  for (int c = 0; c < 64; ++c) {
    float x = a1 + ha2_s[seg*64 + c];
    x = x > 0.f ? x : 0.01f * x;
    mx = fmaxf(mx, x);
  }
  red[seg][rr] = mx;
  __syncthreads();
  if (t < 64) m_s[t] = fmaxf(fmaxf(red[0][t], red[1][t]), fmaxf(red[2][t], red[3][t]));
  __syncthreads();
  const float m = m_s[rr];
  float sum = 0.f;
  for (int c = 0; c < 64; ++c) {
    float x = a1 + ha2_s[seg*64 + c];
    x = x > 0.f ? x : 0.01f * x;
    const float e = __expf(x - m);
    sum += e;
    attimg[rr][seg*64 + c] = f2bf(e);   // unscaled; 1/denom folded into acc
  }
  red[seg][rr] = sum;
  __syncthreads();
  if (t < 64) rd_s[t] = 1.f / (red[0][t] + red[1][t] + red[2][t] + red[3][t]);
  __syncthreads();

  const int w = t >> 6, lane = t & 63, lo = lane & 15, hq = lane >> 4;
  f32x4 acc[4][4];
#pragma unroll
  for (int rt = 0; rt < 4; ++rt)
#pragma unroll
    for (int ct = 0; ct < 4; ++ct) acc[rt][ct] = (f32x4){0.f, 0.f, 0.f, 0.f};

  // attention MFMA: h' = att @ h
  for (int ks = 0; ks < 8; ++ks) {
    bf16x8 a[4];
#pragma unroll
    for (int rt = 0; rt < 4; ++rt)
      a[rt] = *reinterpret_cast<const bf16x8*>(&attimg[rt*16 + lo][ks*32 + hq*8]);
    bf16x8 b[4];
#pragma unroll
    for (int ct = 0; ct < 4; ++ct)
      b[ct] = *reinterpret_cast<const bf16x8*>(hpack + ((size_t)((n*8 + ks)*16 + w*4 + ct)*64 + lane)*8);
#pragma unroll
    for (int rt = 0; rt < 4; ++rt)
#pragma unroll
      for (int ct = 0; ct < 4; ++ct)
        acc[rt][ct] = __builtin_amdgcn_mfma_f32_16x16x32_bf16(a[rt], b[ct], acc[rt][ct], 0, 0, 0);
  }
  __syncthreads();   // all attimg reads done

  // write scaled h' tile back into attimg (row-major, becomes FC1 A-operand)
#pragma unroll
  for (int rt = 0; rt < 4; ++rt)
#pragma unroll
    for (int q = 0; q < 4; ++q) {
      const int row = rt*16 + hq*4 + q;
      const float sc = rd_s[row];
#pragma unroll
      for (int ct = 0; ct < 4; ++ct)
        attimg[row][w*64 + ct*16 + lo] = f2bf(acc[rt][ct][q] * sc);
    }
  __syncthreads();

  // FC1 MFMA: y = [h'|se] @ W1
#pragma unroll
  for (int rt = 0; rt < 4; ++rt)
#pragma unroll
    for (int ct = 0; ct < 4; ++ct) acc[rt][ct] = (f32x4){0.f, 0.f, 0.f, 0.f};
  for (int ks = 0; ks < 16; ++ks) {
    bf16x8 a[4];
    if (ks < 8) {
#pragma unroll
      for (int rt = 0; rt < 4; ++rt)
        a[rt] = *reinterpret_cast<const bf16x8*>(&attimg[rt*16 + lo][ks*32 + hq*8]);
    } else {
#pragma unroll
      for (int rt = 0; rt < 4; ++rt)
        a[rt] = *reinterpret_cast<const bf16x8*>(&se_s[rt*16 + lo][(ks - 8)*32 + hq*8]);
    }
    bf16x8 b[4];
#pragma unroll
    for (int ct = 0; ct < 4; ++ct)
      b[ct] = *reinterpret_cast<const bf16x8*>(w1p + ((size_t)(ks*16 + w*4 + ct)*64 + lane)*8);
#pragma unroll
    for (int rt = 0; rt < 4; ++rt)
#pragma unroll
      for (int ct = 0; ct < 4; ++ct)
        acc[rt][ct] = __builtin_amdgcn_mfma_f32_16x16x32_bf16(a[rt], b[ct], acc[rt][ct], 0, 0, 0);
  }

  // BN1 partial sums (per column) via shfl within column groups
  float s[4] = {0,0,0,0}, ss[4] = {0,0,0,0};
#pragma unroll
  for (int rt = 0; rt < 4; ++rt)
#pragma unroll
    for (int q = 0; q < 4; ++q)
#pragma unroll
      for (int ct = 0; ct < 4; ++ct) {
        const float v = acc[rt][ct][q];
        s[ct] += v; ss[ct] += v * v;
      }
#pragma unroll
  for (int off = 16; off < 64; off <<= 1)
#pragma unroll
    for (int ct = 0; ct < 4; ++ct) {
      s[ct] += __shfl_xor(s[ct], off);
      ss[ct] += __shfl_xor(ss[ct], off);
    }
  if (hq == 0)
#pragma unroll
    for (int ct = 0; ct < 4; ++ct) {
      const int col = w*64 + ct*16 + lo;
      atomicAdd(&st[col], s[ct]);
      atomicAdd(&st[256 + col], ss[ct]);
    }
  __syncthreads();   // attimg reads (FC1) done

  // y tile into attimg, then coalesced store
#pragma unroll
  for (int rt = 0; rt < 4; ++rt)
#pragma unroll
    for (int q = 0; q < 4; ++q) {
      const int row = rt*16 + hq*4 + q;
#pragma unroll
      for (int ct = 0; ct < 4; ++ct)
        attimg[row][w*64 + ct*16 + lo] = f2bf(acc[rt][ct][q]);
    }
  __syncthreads();
  const short* img = &attimg[0][0];
#pragma unroll
  for (int j = 0; j < 8; ++j) {
    const int f = j*2048 + t*8, row = f >> 8, col = f & 255;
    *reinterpret_cast<bf16x8*>(y + (size_t)(r0 + row)*256 + col) =
        *reinterpret_cast<const bf16x8*>(img + row*264 + col);
  }
}

// ---- K5: z = relu(bn1(y)) @ W2 + BN2 sums (BN1 finalize fused) -------------
__global__ __launch_bounds__(256) void k5_z(
    const short* __restrict__ y, const short* __restrict__ w2p,
    const float* __restrict__ g1, const float* __restrict__ be1,
    float* __restrict__ st, float* __restrict__ z)
{
  __shared__ __align__(16) short xs[64][264];   // input tile; reused as fp32 z tile
  __shared__ float sc_s[256], sh_s[256];
  const int t = threadIdx.x;
  const int r0 = blockIdx.x * 64;
  {
    const float mean = st[t] * (1.f / kNV);
    const float var  = st[256 + t] * (1.f / kNV) - mean * mean;
    const float sc   = g1[t] / sqrtf(var + kEps);
    sc_s[t] = sc; sh_s[t] = be1[t] - mean * sc;
  }
  __syncthreads();
#pragma unroll
  for (int j = 0; j < 8; ++j) {
    const int f = j*2048 + t*8, row = f >> 8, col = f & 255;
    bf16x8 v = *reinterpret_cast<const bf16x8*>(y + (size_t)(r0 + row)*256 + col);
    bf16x8 ov;
#pragma unroll
    for (int e = 0; e < 8; ++e) {
      const float fv = fmaf(bf2f(v[e]), sc_s[col + e], sh_s[col + e]);
      ov[e] = f2bf(fmaxf(fv, 0.f));
    }
    *reinterpret_cast<bf16x8*>(&xs[row][col]) = ov;
  }
  __syncthreads();

  const int w = t >> 6, lane = t & 63, lo = lane & 15, hq = lane >> 4;
  f32x4 acc[4][2];
#pragma unroll
  for (int rt = 0; rt < 4; ++rt)
#pragma unroll
    for (int ct = 0; ct < 2; ++ct) acc[rt][ct] = (f32x4){0.f, 0.f, 0.f, 0.f};

  for (int ks = 0; ks < 8; ++ks) {
    bf16x8 a[4];
#pragma unroll
    for (int rt = 0; rt < 4; ++rt)
      a[rt] = *reinterpret_cast<const bf16x8*>(&xs[rt*16 + lo][ks*32 + hq*8]);
    bf16x8 b[2];
#pragma unroll
    for (int ct = 0; ct < 2; ++ct)
      b[ct] = *reinterpret_cast<const bf16x8*>(w2p + ((size_t)(ks*8 + w*2 + ct)*64 + lane)*8);
#pragma unroll
    for (int rt = 0; rt < 4; ++rt)
#pragma unroll
      for (int ct = 0; ct < 2; ++ct)
        acc[rt][ct] = __builtin_amdgcn_mfma_f32_16x16x32_bf16(a[rt], b[ct], acc[rt][ct], 0, 0, 0);
  }

  float s[2] = {0,0}, ss[2] = {0,0};
#pragma unroll
  for (int rt = 0; rt < 4; ++rt)
#pragma unroll
    for (int q = 0; q < 4; ++q)
#pragma unroll
      for (int ct = 0; ct < 2; ++ct) {
        const float v = acc[rt][ct][q];
        s[ct] += v; ss[ct] += v * v;
      }
#pragma unroll
  for (int off = 16; off < 64; off <<= 1)
#pragma unroll
    for (int ct = 0; ct < 2; ++ct) {
      s[ct] += __shfl_xor(s[ct], off);
      ss[ct] += __shfl_xor(ss[ct], off);
    }
  if (hq == 0)
#pragma unroll
    for (int ct = 0; ct < 2; ++ct) {
      const int col = w*32 + ct*16 + lo;
      atomicAdd(&st[1024 + col], s[ct]);
      atomicAdd(&st[1152 + col], ss[ct]);
    }
  __syncthreads();   // xs reads done

  // fp32 z tile in xs space, then coalesced float4 store
  float* zimg = reinterpret_cast<float*>(&xs[0][0]);   // stride 132 floats
#pragma unroll
  for (int rt = 0; rt < 4; ++rt)
#pragma unroll
    for (int q = 0; q < 4; ++q) {
      const int row = rt*16 + hq*4 + q;
#pragma unroll
      for (int ct = 0; ct < 2; ++ct)
        zimg[row*132 + w*32 + ct*16 + lo] = acc[rt][ct][q];
    }
  __syncthreads();
#pragma unroll
  for (int j = 0; j < 8; ++j) {   // FIX: was j < 2 — only wrote rows 0..15
    const int f = j*1024 + t*4, row = f >> 7, col = f & 127;
    *reinterpret_cast<float4*>(z + (size_t)(r0 + row)*128 + col) =
        *reinterpret_cast<const float4*>(zimg + row*132 + col);
  }
}

// ---- K7: out = relu(bn2(z)) in place (BN2 finalize fused) ------------------
__global__ __launch_bounds__(256) void k7_out(
    float* __restrict__ z, const float* __restrict__ st,
    const float* __restrict__ g2, const float* __restrict__ be2)
{
  __shared__ float sc_s[128], sh_s[128];
  const int t = threadIdx.x;
  if (t < 128) {
    const float mean = st[1024 + t] * (1.f / kNV);
    const float var  = st[1152 + t] * (1.f / kNV) - mean * mean;
    const float sc   = g2[t] / sqrtf(var + kEps);
    sc_s[t] = sc; sh_s[t] = be2[t] - mean * sc;
  }
  __syncthreads();
#pragma unroll
  for (int j = 0; j < 4; ++j) {
    const size_t idx = (size_t)blockIdx.x*1024 + j*256 + t;
    float4 v = reinterpret_cast<float4*>(z)[idx];
    const int col = (int)((idx * 4) & (kOut - 1));
    v.x = fmaxf(fmaf(v.x, sc_s[col+0], sh_s[col+0]), 0.f);
    v.y = fmaxf(fmaf(v.y, sc_s[col+1], sh_s[col+1]), 0.f);
    v.z = fmaxf(fmaf(v.z, sc_s[col+2], sh_s[col+2]), 0.f);
    v.w = fmaxf(fmaf(v.w, sc_s[col+3], sh_s[col+3]), 0.f);
    reinterpret_cast<float4*>(z)[idx] = v;
  }
}

} // namespace

extern "C" void kernel_launch(void* const* d_in, const int* in_sizes, int n_in,
                              void* d_out, int out_size, void* d_ws, size_t ws_size,
                              hipStream_t stream) {
  const float* obs = (const float*)d_in[0];
  const float* hin = (const float*)d_in[1];
  const float* Ws  = (const float*)d_in[2];
  const float* bs  = (const float*)d_in[3];
  const float* Wv  = (const float*)d_in[4];
  const float* bv  = (const float*)d_in[5];
  const float* Wg  = (const float*)d_in[6];
  const float* a_w = (const float*)d_in[7];
  const float* W1  = (const float*)d_in[8];
  // d_in[9] = b1: cancels in batchnorm
  const float* g1  = (const float*)d_in[10];
  const float* be1 = (const float*)d_in[11];
  const float* W2  = (const float*)d_in[12];
  // d_in[13] = b2: cancels in batchnorm
  const float* g2  = (const float*)d_in[14];
  const float* be2 = (const float*)d_in[15];

  char* base = (char*)d_ws;
  short* hpack = (short*)(base);                 // 33.5 MB
  short* y     = (short*)(base + 33554432);      // 33.5 MB
  float* ha1   = (float*)(base + 67108864);      // 256 KB
  float* ha2   = (float*)(base + 67371008);      // 256 KB
  float* st    = (float*)(base + 67633152);      // 6 KB
  short* wgp   = (short*)(base + 67639296);      // 288 KB
  short* w1p   = (short*)(base + 67934208);      // 256 KB
  short* w2p   = (short*)(base + 68196352);      // 64 KB
  float* z     = (float*)d_out;

  kpack       <<<152,  256, 0, stream>>>(Wg, W1, W2, wgp, w1p, w2p, st);
  k1_encode   <<<1024, 256, 0, stream>>>(obs, hin, Ws, bs, Wv, bv, wgp, a_w, hpack, ha1, ha2);
  k23_attn_fc1<<<1024, 256, 0, stream>>>(ha1, ha2, hpack, obs, Ws, bs, w1p, y, st);
  k5_z        <<<1024, 256, 0, stream>>>(y, w2p, g1, be1, st, z);
  k7_out      <<<2048, 256, 0, stream>>>(z, st, g2, be2);
}

// Round 5
// 149.422 us; speedup vs baseline: 5.0100x; 1.0389x over previous
//
#include <hip/hip_runtime.h>
#include <math.h>

namespace {

constexpr int kH = 256, kOut = 128;
constexpr int kNV = 65536;
constexpr float kEps = 1e-5f;

typedef __attribute__((ext_vector_type(8))) short bf16x8;
typedef __attribute__((ext_vector_type(4))) float f32x4;
typedef unsigned int u32;

__device__ inline short f2bf(float f) {
  union { float f; u32 u; } v; v.f = f;
  u32 r = v.u + 0x7fffu + ((v.u >> 16) & 1u);
  return (short)(r >> 16);
}
__device__ inline float bf2f(short s) {
  union { float f; u32 u; } v; v.u = ((u32)(unsigned short)s) << 16; return v.f;
}

// ---- KP: pack Wg/W1/W2 into MFMA B-fragment order; compute wga = Wg@[a1|a2];
//          zero stats.
__global__ __launch_bounds__(256) void kpack(
    const float* __restrict__ Wg, const float* __restrict__ W1,
    const float* __restrict__ W2, const float* __restrict__ a_w,
    short* __restrict__ wgp, short* __restrict__ w1p, short* __restrict__ w2p,
    float* __restrict__ wga, float* __restrict__ st)
{
  const int bid = blockIdx.x, t = threadIdx.x;
  if (bid >= 152) {                     // wga blocks (152..159)
    const int b = bid - 152;
    if (t < 144) {
      const int col = t & 1, k = b * 72 + (t >> 1);
      if (k < 576) {
        const float* rowp = Wg + (size_t)k * 256;
        const float* ap = a_w + col * 256;
        float s0 = 0.f, s1 = 0.f, s2 = 0.f, s3 = 0.f;
        for (int c = 0; c < 256; c += 4) {
          s0 = fmaf(rowp[c+0], ap[c+0], s0);
          s1 = fmaf(rowp[c+1], ap[c+1], s1);
          s2 = fmaf(rowp[c+2], ap[c+2], s2);
          s3 = fmaf(rowp[c+3], ap[c+3], s3);
        }
        wga[col * 576 + k] = (s0 + s1) + (s2 + s3);
      }
    }
    return;
  }
  if (bid == 0) {
#pragma unroll
    for (int i = 0; i < 6; ++i) st[i*256 + t] = 0.f;
  }
  const int uid = bid * 256 + t;
  const float* src; short* dst; int N; int u;
  if (uid < 18432)            { src = Wg; dst = wgp; N = 256; u = uid; }
  else if (uid < 34816)       { src = W1; dst = w1p; N = 256; u = uid - 18432; }
  else if (uid < 38912)       { src = W2; dst = w2p; N = 128; u = uid - 34816; }
  else return;
  const int lane = u & 63, ctkt = u >> 6;
  const int nct = N >> 4;
  const int kt = ctkt / nct, ct = ctkt % nct;
  const int row = kt * 32 + (lane >> 4) * 8;
  const int col = ct * 16 + (lane & 15);
  bf16x8 ov;
#pragma unroll
  for (int e = 0; e < 8; ++e) ov[e] = f2bf(src[(size_t)(row + e) * N + col]);
  *reinterpret_cast<bf16x8*>(dst + (size_t)u * 8) = ov;
}

// ---- K1: 32-row tile. comb=[se|ve|hi] (LDS bf16), h = comb@Wg (MFMA),
//          ha1/ha2 via extra wga B-tile on wave 0; h stored packed-B.
__global__ __launch_bounds__(256) void k1_encode(
    const float* __restrict__ obs, const float* __restrict__ hin,
    const float* __restrict__ Ws, const float* __restrict__ bs,
    const float* __restrict__ Wv, const float* __restrict__ bv,
    const short* __restrict__ wgp, const float* __restrict__ wga,
    short* __restrict__ hpack, float* __restrict__ ha1, float* __restrict__ ha2)
{
  __shared__ __align__(16) short comb[32][584];   // 37376 B; reused as pack image
  __shared__ float wga_s[1152];
  __shared__ float obs_s[32][4];
  const int t = threadIdx.x;
  const int xcd = blockIdx.x & 7, ib = blockIdx.x >> 3;
  const int workid = xcd * 256 + ib;              // 0..2047, XCD-contiguous
  const int r0 = workid * 32;

  if (t < 128) obs_s[t >> 2][t & 3] = obs[(size_t)(r0 + (t >> 2)) * 5 + 1 + (t & 3)];
#pragma unroll
  for (int j = 0; j < 5; ++j) {
    const int u = t + j * 256;
    if (u < 1152) wga_s[u] = wga[u];
  }
  // hi tile: 2048 floats -> comb cols 512..575
#pragma unroll
  for (int jj = 0; jj < 2; ++jj) {
    const int f = jj * 1024 + t * 4;
    const int row = f >> 6, c = f & 63;
    const float4 v = *reinterpret_cast<const float4*>(hin + (size_t)r0 * 64 + f);
    short4 o;
    o.x = f2bf(v.x); o.y = f2bf(v.y); o.z = f2bf(v.z); o.w = f2bf(v.w);
    *reinterpret_cast<short4*>(&comb[row][512 + c]) = o;
  }
  const float ws0 = Ws[t], ws1 = Ws[256 + t], bsv = bs[t];
  const float wv0 = Wv[t], wv1 = Wv[256 + t], bvv = bv[t];
  __syncthreads();
  for (int r = 0; r < 32; ++r) {
    const float o1 = obs_s[r][0], o2 = obs_s[r][1], o3 = obs_s[r][2], o4 = obs_s[r][3];
    const float sv = fmaf(o2, ws1, fmaf(o1, ws0, bsv));
    comb[r][t] = f2bf(fmaxf(sv, 0.f));
    const float vv = fmaf(o4, wv1, fmaf(o3, wv0, bvv));
    comb[r][256 + t] = f2bf(fmaxf(vv, 0.f));
  }
  __syncthreads();

  const int w = t >> 6, lane = t & 63, lo = lane & 15, hq = lane >> 4;
  f32x4 acc[2][4];
  f32x4 accE[2];
#pragma unroll
  for (int rt = 0; rt < 2; ++rt) {
    accE[rt] = (f32x4){0.f, 0.f, 0.f, 0.f};
#pragma unroll
    for (int ct = 0; ct < 4; ++ct) acc[rt][ct] = (f32x4){0.f, 0.f, 0.f, 0.f};
  }

  for (int ks = 0; ks < 18; ++ks) {
    bf16x8 a[2];
#pragma unroll
    for (int rt = 0; rt < 2; ++rt)
      a[rt] = *reinterpret_cast<const bf16x8*>(&comb[rt*16 + lo][ks*32 + hq*8]);
    bf16x8 b[4];
#pragma unroll
    for (int ct = 0; ct < 4; ++ct)
      b[ct] = *reinterpret_cast<const bf16x8*>(wgp + ((size_t)(ks*16 + w*4 + ct)*64 + lane)*8);
#pragma unroll
    for (int rt = 0; rt < 2; ++rt)
#pragma unroll
      for (int ct = 0; ct < 4; ++ct)
        acc[rt][ct] = __builtin_amdgcn_mfma_f32_16x16x32_bf16(a[rt], b[ct], acc[rt][ct], 0, 0, 0);
    if (w == 0) {               // wave-uniform branch: ha tile
      bf16x8 be;
#pragma unroll
      for (int e = 0; e < 8; ++e) {
        const float f = (lo < 2) ? wga_s[lo*576 + ks*32 + hq*8 + e] : 0.f;
        be[e] = f2bf(f);
      }
#pragma unroll
      for (int rt = 0; rt < 2; ++rt)
        accE[rt] = __builtin_amdgcn_mfma_f32_16x16x32_bf16(a[rt], be, accE[rt], 0, 0, 0);
    }
  }
  if (w == 0 && lo < 2) {
    float* dst = (lo == 0) ? ha1 : ha2;
#pragma unroll
    for (int rt = 0; rt < 2; ++rt)
#pragma unroll
      for (int q = 0; q < 4; ++q)
        dst[r0 + rt*16 + hq*4 + q] = accE[rt][q];
  }
  __syncthreads();   // comb MFMA reads done

  // 16 KB pack image in comb space: (ctg*64 + khi*16 + lo)*8 + e
  short* pimg = reinterpret_cast<short*>(&comb[0][0]);
#pragma unroll
  for (int rt = 0; rt < 2; ++rt)
#pragma unroll
    for (int ct = 0; ct < 4; ++ct) {
      const int base = (((w*4 + ct)*64) + (rt*2 + (hq>>1))*16 + lo)*8 + (hq&1)*4;
      short4 val;
      val.x = f2bf(acc[rt][ct][0]); val.y = f2bf(acc[rt][ct][1]);
      val.z = f2bf(acc[rt][ct][2]); val.w = f2bf(acc[rt][ct][3]);
      *reinterpret_cast<short4*>(pimg + base) = val;
    }
  __syncthreads();

  short* dst = hpack + (size_t)workid * 8192;   // slab (n*8 + kt) == workid
#pragma unroll
  for (int j = 0; j < 4; ++j)
    *reinterpret_cast<bf16x8*>(dst + j*2048 + t*8) =
        *reinterpret_cast<const bf16x8*>(pimg + j*2048 + t*8);
}

// ---- K23: softmax (single-pass, no max) + h'=att@h + y=[h'|se]@W1 + BN1 sums
__global__ __launch_bounds__(256, 4) void k23_attn_fc1(
    const float* __restrict__ ha1g, const float* __restrict__ ha2g,
    const short* __restrict__ hpack, const float* __restrict__ obs,
    const float* __restrict__ Ws, const float* __restrict__ bs,
    const short* __restrict__ w1p, short* __restrict__ y, float* __restrict__ st)
{
  __shared__ __align__(16) short attimg[64][264];  // att -> h' -> se -> y tile
  __shared__ float ws_s[768];                      // Ws row0 | Ws row1 | bs
  __shared__ float ha2_s[256];
  __shared__ float ha1_s[64], rd_s[64];
  __shared__ float red[4][64];
  __shared__ float obs_s[64][2];
  const int t = threadIdx.x;
  const int xcd = blockIdx.x & 7, ib = blockIdx.x >> 3;
  const int workid = xcd * 128 + ib;               // 0..1023, XCD-contiguous
  const int r0 = workid * 64;
  const int n = r0 >> 8;

  ws_s[t] = Ws[t]; ws_s[256 + t] = Ws[256 + t]; ws_s[512 + t] = bs[t];
  ha2_s[t] = ha2g[n*256 + t];
  if (t < 64) ha1_s[t] = ha1g[r0 + t];
  if (t < 128) obs_s[t >> 1][t & 1] = obs[(size_t)(r0 + (t >> 1)) * 5 + 1 + (t & 1)];
  __syncthreads();

  // single-pass softmax numerator (|x| small -> exp safe without max-sub)
  const int rr = t & 63, seg = t >> 6;
  {
    const float a1 = ha1_s[rr];
    float sum = 0.f;
    for (int c8 = 0; c8 < 8; ++c8) {
      bf16x8 pk;
#pragma unroll
      for (int e = 0; e < 8; ++e) {
        float x = a1 + ha2_s[seg*64 + c8*8 + e];
        x = fmaxf(x, 0.01f * x);          // leaky_relu
        const float ev = __expf(x);
        sum += ev;
        pk[e] = f2bf(ev);
      }
      *reinterpret_cast<bf16x8*>(&attimg[rr][seg*64 + c8*8]) = pk;
    }
    red[seg][rr] = sum;
  }
  __syncthreads();
  if (t < 64) rd_s[t] = 1.f / (red[0][t] + red[1][t] + red[2][t] + red[3][t]);
  __syncthreads();

  const int w = t >> 6, lane = t & 63, lo = lane & 15, hq = lane >> 4;
  f32x4 acc[4][4];
#pragma unroll
  for (int rt = 0; rt < 4; ++rt)
#pragma unroll
    for (int ct = 0; ct < 4; ++ct) acc[rt][ct] = (f32x4){0.f, 0.f, 0.f, 0.f};

  // MFMA1: h' = att @ h  (B prefetched from hpack, depth 1)
  {
    const short* bB = hpack + (size_t)n*65536 + ((size_t)(w*4)*64 + lane)*8;
    bf16x8 bb[4];
#pragma unroll
    for (int ct = 0; ct < 4; ++ct) bb[ct] = *reinterpret_cast<const bf16x8*>(bB + ct*512);
    for (int ks = 0; ks < 8; ++ks) {
      bf16x8 bn[4];
      if (ks < 7) {
#pragma unroll
        for (int ct = 0; ct < 4; ++ct)
          bn[ct] = *reinterpret_cast<const bf16x8*>(bB + (ks+1)*8192 + ct*512);
      }
      bf16x8 a[4];
#pragma unroll
      for (int rt = 0; rt < 4; ++rt)
        a[rt] = *reinterpret_cast<const bf16x8*>(&attimg[rt*16 + lo][ks*32 + hq*8]);
#pragma unroll
      for (int rt = 0; rt < 4; ++rt)
#pragma unroll
        for (int ct = 0; ct < 4; ++ct)
          acc[rt][ct] = __builtin_amdgcn_mfma_f32_16x16x32_bf16(a[rt], bb[ct], acc[rt][ct], 0, 0, 0);
      if (ks < 7) {
#pragma unroll
        for (int ct = 0; ct < 4; ++ct) bb[ct] = bn[ct];
      }
    }
  }
  __syncthreads();   // attimg (att) reads done

  // scaled h' into attimg
#pragma unroll
  for (int rt = 0; rt < 4; ++rt)
#pragma unroll
    for (int q = 0; q < 4; ++q) {
      const int row = rt*16 + hq*4 + q;
      const float sc = rd_s[row];
#pragma unroll
      for (int ct = 0; ct < 4; ++ct)
        attimg[row][w*64 + ct*16 + lo] = f2bf(acc[rt][ct][q] * sc);
    }
  __syncthreads();

  // MFMA2a: y += h' @ W1[0:256]
  f32x4 accY[4][4];
#pragma unroll
  for (int rt = 0; rt < 4; ++rt)
#pragma unroll
    for (int ct = 0; ct < 4; ++ct) accY[rt][ct] = (f32x4){0.f, 0.f, 0.f, 0.f};
  const short* w1B = w1p + ((size_t)(w*4)*64 + lane)*8;
  {
    bf16x8 bb[4];
#pragma unroll
    for (int ct = 0; ct < 4; ++ct) bb[ct] = *reinterpret_cast<const bf16x8*>(w1B + ct*512);
    for (int ks = 0; ks < 8; ++ks) {
      bf16x8 bn[4];
      if (ks < 7) {
#pragma unroll
        for (int ct = 0; ct < 4; ++ct)
          bn[ct] = *reinterpret_cast<const bf16x8*>(w1B + (ks+1)*8192 + ct*512);
      }
      bf16x8 a[4];
#pragma unroll
      for (int rt = 0; rt < 4; ++rt)
        a[rt] = *reinterpret_cast<const bf16x8*>(&attimg[rt*16 + lo][ks*32 + hq*8]);
#pragma unroll
      for (int rt = 0; rt < 4; ++rt)
#pragma unroll
        for (int ct = 0; ct < 4; ++ct)
          accY[rt][ct] = __builtin_amdgcn_mfma_f32_16x16x32_bf16(a[rt], bb[ct], accY[rt][ct], 0, 0, 0);
      if (ks < 7) {
#pragma unroll
        for (int ct = 0; ct < 4; ++ct) bb[ct] = bn[ct];
      }
    }
  }
  __syncthreads();   // h' reads done

  // build se into attimg (overwrites h')
  {
    const float o1 = obs_s[rr][0], o2 = obs_s[rr][1];
    for (int c8 = 0; c8 < 8; ++c8) {
      const int c = seg*64 + c8*8;
      bf16x8 pk;
#pragma unroll
      for (int e = 0; e < 8; ++e) {
        const float sv = fmaf(o2, ws_s[256 + c + e], fmaf(o1, ws_s[c + e], ws_s[512 + c + e]));
        pk[e] = f2bf(fmaxf(sv, 0.f));
      }
      *reinterpret_cast<bf16x8*>(&attimg[rr][c]) = pk;
    }
  }
  __syncthreads();

  // MFMA2b: y += se @ W1[256:512]
  {
    bf16x8 bb[4];
#pragma unroll
    for (int ct = 0; ct < 4; ++ct)
      bb[ct] = *reinterpret_cast<const bf16x8*>(w1B + 8*8192 + ct*512);
    for (int ks = 0; ks < 8; ++ks) {
      bf16x8 bn[4];
      if (ks < 7) {
#pragma unroll
        for (int ct = 0; ct < 4; ++ct)
          bn[ct] = *reinterpret_cast<const bf16x8*>(w1B + (ks+9)*8192 + ct*512);
      }
      bf16x8 a[4];
#pragma unroll
      for (int rt = 0; rt < 4; ++rt)
        a[rt] = *reinterpret_cast<const bf16x8*>(&attimg[rt*16 + lo][ks*32 + hq*8]);
#pragma unroll
      for (int rt = 0; rt < 4; ++rt)
#pragma unroll
        for (int ct = 0; ct < 4; ++ct)
          accY[rt][ct] = __builtin_amdgcn_mfma_f32_16x16x32_bf16(a[rt], bb[ct], accY[rt][ct], 0, 0, 0);
      if (ks < 7) {
#pragma unroll
        for (int ct = 0; ct < 4; ++ct) bb[ct] = bn[ct];
      }
    }
  }

  // BN1 partial sums
  float s[4] = {0,0,0,0}, ss[4] = {0,0,0,0};
#pragma unroll
  for (int rt = 0; rt < 4; ++rt)
#pragma unroll
    for (int q = 0; q < 4; ++q)
#pragma unroll
      for (int ct = 0; ct < 4; ++ct) {
        const float v = accY[rt][ct][q];
        s[ct] += v; ss[ct] += v * v;
      }
#pragma unroll
  for (int off = 16; off < 64; off <<= 1)
#pragma unroll
    for (int ct = 0; ct < 4; ++ct) {
      s[ct] += __shfl_xor(s[ct], off);
      ss[ct] += __shfl_xor(ss[ct], off);
    }
  if (hq == 0)
#pragma unroll
    for (int ct = 0; ct < 4; ++ct) {
      const int col = w*64 + ct*16 + lo;
      atomicAdd(&st[col], s[ct]);
      atomicAdd(&st[256 + col], ss[ct]);
    }
  __syncthreads();   // se reads done

  // y tile into attimg, coalesced store
#pragma unroll
  for (int rt = 0; rt < 4; ++rt)
#pragma unroll
    for (int q = 0; q < 4; ++q) {
      const int row = rt*16 + hq*4 + q;
#pragma unroll
      for (int ct = 0; ct < 4; ++ct)
        attimg[row][w*64 + ct*16 + lo] = f2bf(accY[rt][ct][q]);
    }
  __syncthreads();
  const short* img = &attimg[0][0];
#pragma unroll
  for (int j = 0; j < 8; ++j) {
    const int f = j*2048 + t*8, row = f >> 8, col = f & 255;
    *reinterpret_cast<bf16x8*>(y + (size_t)(r0 + row)*256 + col) =
        *reinterpret_cast<const bf16x8*>(img + row*264 + col);
  }
}

// ---- K5: z = relu(bn1(y)) @ W2 + BN2 sums; z stored bf16 -------------------
__global__ __launch_bounds__(256) void k5_z(
    const short* __restrict__ y, const short* __restrict__ w2p,
    const float* __restrict__ g1, const float* __restrict__ be1,
    float* __restrict__ st, short* __restrict__ zb)
{
  __shared__ __align__(16) short xs[64][264];
  __shared__ float sc_s[256], sh_s[256];
  const int t = threadIdx.x;
  const int r0 = blockIdx.x * 64;
  {
    const float mean = st[t] * (1.f / kNV);
    const float var  = st[256 + t] * (1.f / kNV) - mean * mean;
    const float sc   = g1[t] / sqrtf(var + kEps);
    sc_s[t] = sc; sh_s[t] = be1[t] - mean * sc;
  }
  __syncthreads();
#pragma unroll
  for (int j = 0; j < 8; ++j) {
    const int f = j*2048 + t*8, row = f >> 8, col = f & 255;
    bf16x8 v = *reinterpret_cast<const bf16x8*>(y + (size_t)(r0 + row)*256 + col);
    bf16x8 ov;
#pragma unroll
    for (int e = 0; e < 8; ++e) {
      const float fv = fmaf(bf2f(v[e]), sc_s[col + e], sh_s[col + e]);
      ov[e] = f2bf(fmaxf(fv, 0.f));
    }
    *reinterpret_cast<bf16x8*>(&xs[row][col]) = ov;
  }
  __syncthreads();

  const int w = t >> 6, lane = t & 63, lo = lane & 15, hq = lane >> 4;
  f32x4 acc[4][2];
#pragma unroll
  for (int rt = 0; rt < 4; ++rt)
#pragma unroll
    for (int ct = 0; ct < 2; ++ct) acc[rt][ct] = (f32x4){0.f, 0.f, 0.f, 0.f};

  {
    const short* w2B = w2p + ((size_t)(w*2)*64 + lane)*8;
    bf16x8 bb[2];
#pragma unroll
    for (int ct = 0; ct < 2; ++ct) bb[ct] = *reinterpret_cast<const bf16x8*>(w2B + ct*512);
    for (int ks = 0; ks < 8; ++ks) {
      bf16x8 bn[2];
      if (ks < 7) {
#pragma unroll
        for (int ct = 0; ct < 2; ++ct)
          bn[ct] = *reinterpret_cast<const bf16x8*>(w2B + (ks+1)*4096 + ct*512);
      }
      bf16x8 a[4];
#pragma unroll
      for (int rt = 0; rt < 4; ++rt)
        a[rt] = *reinterpret_cast<const bf16x8*>(&xs[rt*16 + lo][ks*32 + hq*8]);
#pragma unroll
      for (int rt = 0; rt < 4; ++rt)
#pragma unroll
        for (int ct = 0; ct < 2; ++ct)
          acc[rt][ct] = __builtin_amdgcn_mfma_f32_16x16x32_bf16(a[rt], bb[ct], acc[rt][ct], 0, 0, 0);
      if (ks < 7) {
#pragma unroll
        for (int ct = 0; ct < 2; ++ct) bb[ct] = bn[ct];
      }
    }
  }

  float s[2] = {0,0}, ss[2] = {0,0};
#pragma unroll
  for (int rt = 0; rt < 4; ++rt)
#pragma unroll
    for (int q = 0; q < 4; ++q)
#pragma unroll
      for (int ct = 0; ct < 2; ++ct) {
        const float v = acc[rt][ct][q];
        s[ct] += v; ss[ct] += v * v;
      }
#pragma unroll
  for (int off = 16; off < 64; off <<= 1)
#pragma unroll
    for (int ct = 0; ct < 2; ++ct) {
      s[ct] += __shfl_xor(s[ct], off);
      ss[ct] += __shfl_xor(ss[ct], off);
    }
  if (hq == 0)
#pragma unroll
    for (int ct = 0; ct < 2; ++ct) {
      const int col = w*32 + ct*16 + lo;
      atomicAdd(&st[1024 + col], s[ct]);
      atomicAdd(&st[1152 + col], ss[ct]);
    }
  __syncthreads();   // xs reads done

  // bf16 z tile (stride 136), coalesced store
  short* zimg = reinterpret_cast<short*>(&xs[0][0]);
#pragma unroll
  for (int rt = 0; rt < 4; ++rt)
#pragma unroll
    for (int q = 0; q < 4; ++q) {
      const int row = rt*16 + hq*4 + q;
#pragma unroll
      for (int ct = 0; ct < 2; ++ct)
        zimg[row*136 + w*32 + ct*16 + lo] = f2bf(acc[rt][ct][q]);
    }
  __syncthreads();
#pragma unroll
  for (int j = 0; j < 4; ++j) {
    const int f = j*2048 + t*8, row = f >> 7, col = f & 127;
    *reinterpret_cast<bf16x8*>(zb + (size_t)(r0 + row)*128 + col) =
        *reinterpret_cast<const bf16x8*>(zimg + row*136 + col);
  }
}

// ---- K7: out = relu(bn2(z)) -- bf16 in, fp32 out ---------------------------
__global__ __launch_bounds__(256) void k7_out(
    const short* __restrict__ zb, const float* __restrict__ st,
    const float* __restrict__ g2, const float* __restrict__ be2,
    float* __restrict__ out)
{
  __shared__ float sc_s[128], sh_s[128];
  const int t = threadIdx.x;
  if (t < 128) {
    const float mean = st[1024 + t] * (1.f / kNV);
    const float var  = st[1152 + t] * (1.f / kNV) - mean * mean;
    const float sc   = g2[t] / sqrtf(var + kEps);
    sc_s[t] = sc; sh_s[t] = be2[t] - mean * sc;
  }
  __syncthreads();
#pragma unroll
  for (int j = 0; j < 2; ++j) {
    const size_t u = (size_t)blockIdx.x * 512 + j*256 + t;  // 8-elem unit
    bf16x8 v = *reinterpret_cast<const bf16x8*>(zb + u*8);
    const int col = ((int)u & 15) * 8;
    float4 r0, r1;
    r0.x = fmaxf(fmaf(bf2f(v[0]), sc_s[col+0], sh_s[col+0]), 0.f);
    r0.y = fmaxf(fmaf(bf2f(v[1]), sc_s[col+1], sh_s[col+1]), 0.f);
    r0.z = fmaxf(fmaf(bf2f(v[2]), sc_s[col+2], sh_s[col+2]), 0.f);
    r0.w = fmaxf(fmaf(bf2f(v[3]), sc_s[col+3], sh_s[col+3]), 0.f);
    r1.x = fmaxf(fmaf(bf2f(v[4]), sc_s[col+4], sh_s[col+4]), 0.f);
    r1.y = fmaxf(fmaf(bf2f(v[5]), sc_s[col+5], sh_s[col+5]), 0.f);
    r1.z = fmaxf(fmaf(bf2f(v[6]), sc_s[col+6], sh_s[col+6]), 0.f);
    r1.w = fmaxf(fmaf(bf2f(v[7]), sc_s[col+7], sh_s[col+7]), 0.f);
    *reinterpret_cast<float4*>(out + u*8)     = r0;
    *reinterpret_cast<float4*>(out + u*8 + 4) = r1;
  }
}

} // namespace

extern "C" void kernel_launch(void* const* d_in, const int* in_sizes, int n_in,
                              void* d_out, int out_size, void* d_ws, size_t ws_size,
                              hipStream_t stream) {
  const float* obs = (const float*)d_in[0];
  const float* hin = (const float*)d_in[1];
  const float* Ws  = (const float*)d_in[2];
  const float* bs  = (const float*)d_in[3];
  const float* Wv  = (const float*)d_in[4];
  const float* bv  = (const float*)d_in[5];
  const float* Wg  = (const float*)d_in[6];
  const float* a_w = (const float*)d_in[7];
  const float* W1  = (const float*)d_in[8];
  // d_in[9] = b1: cancels in batchnorm
  const float* g1  = (const float*)d_in[10];
  const float* be1 = (const float*)d_in[11];
  const float* W2  = (const float*)d_in[12];
  // d_in[13] = b2: cancels in batchnorm
  const float* g2  = (const float*)d_in[14];
  const float* be2 = (const float*)d_in[15];

  char* base = (char*)d_ws;
  short* hpack = (short*)(base);                 // 33.5 MB
  short* y     = (short*)(base + 33554432);      // 33.5 MB
  short* zb    = (short*)(base + 67108864);      // 16.8 MB
  float* ha1   = (float*)(base + 83886080);      // 256 KB
  float* ha2   = (float*)(base + 84148224);      // 256 KB
  float* st    = (float*)(base + 84410368);      // 6 KB
  short* wgp   = (short*)(base + 84416512);      // 288 KB
  short* w1p   = (short*)(base + 84711424);      // 256 KB
  short* w2p   = (short*)(base + 84973568);      // 64 KB
  float* wga   = (float*)(base + 85039104);      // 4.6 KB
  float* out   = (float*)d_out;

  kpack       <<<160,  256, 0, stream>>>(Wg, W1, W2, a_w, wgp, w1p, w2p, wga, st);
  k1_encode   <<<2048, 256, 0, stream>>>(obs, hin, Ws, bs, Wv, bv, wgp, wga, hpack, ha1, ha2);
  k23_attn_fc1<<<1024, 256, 0, stream>>>(ha1, ha2, hpack, obs, Ws, bs, w1p, y, st);
  k5_z        <<<1024, 256, 0, stream>>>(y, w2p, g1, be1, st, zb);
  k7_out      <<<2048, 256, 0, stream>>>(zb, st, g2, be2, out);
}

// Round 6
// 138.732 us; speedup vs baseline: 5.3961x; 1.0771x over previous
//
#include <hip/hip_runtime.h>
#include <math.h>

namespace {

constexpr int kH = 256, kOut = 128;
constexpr int kNV = 65536;
constexpr float kEps = 1e-5f;

typedef __attribute__((ext_vector_type(8))) short bf16x8;
typedef __attribute__((ext_vector_type(4))) float f32x4;
typedef unsigned int u32;

__device__ inline short f2bf(float f) {
  union { float f; u32 u; } v; v.f = f;
  u32 r = v.u + 0x7fffu + ((v.u >> 16) & 1u);
  return (short)(r >> 16);
}
__device__ inline float bf2f(short s) {
  union { float f; u32 u; } v; v.u = ((u32)(unsigned short)s) << 16; return v.f;
}

// ---- KP: pack Wg/W1/W2 into MFMA B-fragment order; wgab = Wg@[a1|a2] in
//          bf16 B-fragment order; zero stats.
__global__ __launch_bounds__(256) void kpack(
    const float* __restrict__ Wg, const float* __restrict__ W1,
    const float* __restrict__ W2, const float* __restrict__ a_w,
    short* __restrict__ wgp, short* __restrict__ w1p, short* __restrict__ w2p,
    short* __restrict__ wgab, float* __restrict__ st)
{
  const int bid = blockIdx.x, t = threadIdx.x;
  if (bid >= 152) {                     // wgab blocks (152..159)
    const int b = bid - 152;
    if (t < 144) {
      const int col = t & 1, k = b * 72 + (t >> 1);
      if (k < 576) {
        const float* rowp = Wg + (size_t)k * 256;
        const float* ap = a_w + col * 256;
        float s0 = 0.f, s1 = 0.f, s2 = 0.f, s3 = 0.f;
        for (int c = 0; c < 256; c += 4) {
          s0 = fmaf(rowp[c+0], ap[c+0], s0);
          s1 = fmaf(rowp[c+1], ap[c+1], s1);
          s2 = fmaf(rowp[c+2], ap[c+2], s2);
          s3 = fmaf(rowp[c+3], ap[c+3], s3);
        }
        const int ks = k >> 5, r = k & 31, hq = r >> 3, e = r & 7;
        wgab[((ks*2 + col)*4 + hq)*8 + e] = f2bf((s0 + s1) + (s2 + s3));
      }
    }
    return;
  }
  if (bid == 0) {
#pragma unroll
    for (int i = 0; i < 6; ++i) st[i*256 + t] = 0.f;
  }
  const int uid = bid * 256 + t;
  const float* src; short* dst; int N; int u;
  if (uid < 18432)            { src = Wg; dst = wgp; N = 256; u = uid; }
  else if (uid < 34816)       { src = W1; dst = w1p; N = 256; u = uid - 18432; }
  else if (uid < 38912)       { src = W2; dst = w2p; N = 128; u = uid - 34816; }
  else return;
  const int lane = u & 63, ctkt = u >> 6;
  const int nct = N >> 4;
  const int kt = ctkt / nct, ct = ctkt % nct;
  const int row = kt * 32 + (lane >> 4) * 8;
  const int col = ct * 16 + (lane & 15);
  bf16x8 ov;
#pragma unroll
  for (int e = 0; e < 8; ++e) ov[e] = f2bf(src[(size_t)(row + e) * N + col]);
  *reinterpret_cast<bf16x8*>(dst + (size_t)u * 8) = ov;
}

// ---- K1: 32-row tile. comb=[se|ve|hi] (LDS bf16), h = comb@Wg (MFMA),
//          ha1/ha2 via wgab B-tile on wave 0; h stored packed-B.
//          4 blocks/CU, depth-1 B prefetch.
__global__ __launch_bounds__(256, 4) void k1_encode(
    const float* __restrict__ obs, const float* __restrict__ hin,
    const float* __restrict__ Ws, const float* __restrict__ bs,
    const float* __restrict__ Wv, const float* __restrict__ bv,
    const short* __restrict__ wgp, const short* __restrict__ wgab,
    short* __restrict__ hpack, float* __restrict__ ha1, float* __restrict__ ha2)
{
  __shared__ __align__(16) short comb[32][584];   // 37376 B; reused as pack image
  __shared__ float obs_s[32][4];
  const int t = threadIdx.x;
  const int xcd = blockIdx.x & 7, ib = blockIdx.x >> 3;
  const int workid = xcd * 256 + ib;              // 0..2047, XCD-contiguous
  const int r0 = workid * 32;

  if (t < 128) obs_s[t >> 2][t & 3] = obs[(size_t)(r0 + (t >> 2)) * 5 + 1 + (t & 3)];
  // hi tile: 2048 floats -> comb cols 512..575
#pragma unroll
  for (int jj = 0; jj < 2; ++jj) {
    const int f = jj * 1024 + t * 4;
    const int row = f >> 6, c = f & 63;
    const float4 v = *reinterpret_cast<const float4*>(hin + (size_t)r0 * 64 + f);
    short4 o;
    o.x = f2bf(v.x); o.y = f2bf(v.y); o.z = f2bf(v.z); o.w = f2bf(v.w);
    *reinterpret_cast<short4*>(&comb[row][512 + c]) = o;
  }
  const float ws0 = Ws[t], ws1 = Ws[256 + t], bsv = bs[t];
  const float wv0 = Wv[t], wv1 = Wv[256 + t], bvv = bv[t];
  __syncthreads();
  for (int r = 0; r < 32; ++r) {
    const float o1 = obs_s[r][0], o2 = obs_s[r][1], o3 = obs_s[r][2], o4 = obs_s[r][3];
    const float sv = fmaf(o2, ws1, fmaf(o1, ws0, bsv));
    comb[r][t] = f2bf(fmaxf(sv, 0.f));
    const float vv = fmaf(o4, wv1, fmaf(o3, wv0, bvv));
    comb[r][256 + t] = f2bf(fmaxf(vv, 0.f));
  }
  __syncthreads();

  const int w = t >> 6, lane = t & 63, lo = lane & 15, hq = lane >> 4;
  f32x4 acc[2][4];
  f32x4 accE[2];
#pragma unroll
  for (int rt = 0; rt < 2; ++rt) {
    accE[rt] = (f32x4){0.f, 0.f, 0.f, 0.f};
#pragma unroll
    for (int ct = 0; ct < 4; ++ct) acc[rt][ct] = (f32x4){0.f, 0.f, 0.f, 0.f};
  }

  const short* wB = wgp + ((size_t)(w*4)*64 + lane)*8;
  bf16x8 bb[4];
#pragma unroll
  for (int ct = 0; ct < 4; ++ct)
    bb[ct] = *reinterpret_cast<const bf16x8*>(wB + ct*512);

#pragma unroll
  for (int ks = 0; ks < 18; ++ks) {
    bf16x8 bn[4];
    if (ks < 17) {
#pragma unroll
      for (int ct = 0; ct < 4; ++ct)
        bn[ct] = *reinterpret_cast<const bf16x8*>(wB + (ks+1)*8192 + ct*512);
    }
    bf16x8 a[2];
#pragma unroll
    for (int rt = 0; rt < 2; ++rt)
      a[rt] = *reinterpret_cast<const bf16x8*>(&comb[rt*16 + lo][ks*32 + hq*8]);
#pragma unroll
    for (int rt = 0; rt < 2; ++rt)
#pragma unroll
      for (int ct = 0; ct < 4; ++ct)
        acc[rt][ct] = __builtin_amdgcn_mfma_f32_16x16x32_bf16(a[rt], bb[ct], acc[rt][ct], 0, 0, 0);
    if (w == 0) {               // wave-uniform branch: ha tile
      bf16x8 be;
      if (lo < 2)
        be = *reinterpret_cast<const bf16x8*>(wgab + ((ks*2 + lo)*4 + hq)*8);
      else
        be = (bf16x8){0,0,0,0,0,0,0,0};
#pragma unroll
      for (int rt = 0; rt < 2; ++rt)
        accE[rt] = __builtin_amdgcn_mfma_f32_16x16x32_bf16(a[rt], be, accE[rt], 0, 0, 0);
    }
    if (ks < 17) {
#pragma unroll
      for (int ct = 0; ct < 4; ++ct) bb[ct] = bn[ct];
    }
  }
  if (w == 0 && lo < 2) {
    float* dst = (lo == 0) ? ha1 : ha2;
#pragma unroll
    for (int rt = 0; rt < 2; ++rt)
#pragma unroll
      for (int q = 0; q < 4; ++q)
        dst[r0 + rt*16 + hq*4 + q] = accE[rt][q];
  }
  __syncthreads();   // comb MFMA reads done

  // 16 KB pack image in comb space: (ctg*64 + khi*16 + lo)*8 + e
  short* pimg = reinterpret_cast<short*>(&comb[0][0]);
#pragma unroll
  for (int rt = 0; rt < 2; ++rt)
#pragma unroll
    for (int ct = 0; ct < 4; ++ct) {
      const int base = (((w*4 + ct)*64) + (rt*2 + (hq>>1))*16 + lo)*8 + (hq&1)*4;
      short4 val;
      val.x = f2bf(acc[rt][ct][0]); val.y = f2bf(acc[rt][ct][1]);
      val.z = f2bf(acc[rt][ct][2]); val.w = f2bf(acc[rt][ct][3]);
      *reinterpret_cast<short4*>(pimg + base) = val;
    }
  __syncthreads();

  short* dst = hpack + (size_t)workid * 8192;   // slab (n*8 + kt) == workid
#pragma unroll
  for (int j = 0; j < 4; ++j)
    *reinterpret_cast<bf16x8*>(dst + j*2048 + t*8) =
        *reinterpret_cast<const bf16x8*>(pimg + j*2048 + t*8);
}

// ---- K23: softmax (single-pass, no max) + h'=att@h + y=[h'|se]@W1 + BN1 sums
__global__ __launch_bounds__(256, 4) void k23_attn_fc1(
    const float* __restrict__ ha1g, const float* __restrict__ ha2g,
    const short* __restrict__ hpack, const float* __restrict__ obs,
    const float* __restrict__ Ws, const float* __restrict__ bs,
    const short* __restrict__ w1p, short* __restrict__ y, float* __restrict__ st)
{
  __shared__ __align__(16) short attimg[64][264];  // att -> h' -> se -> y tile
  __shared__ float ws_s[768];                      // Ws row0 | Ws row1 | bs
  __shared__ float ha2_s[256];
  __shared__ float ha1_s[64], rd_s[64];
  __shared__ float red[4][64];
  __shared__ float obs_s[64][2];
  const int t = threadIdx.x;
  const int xcd = blockIdx.x & 7, ib = blockIdx.x >> 3;
  const int workid = xcd * 128 + ib;               // 0..1023, XCD-contiguous
  const int r0 = workid * 64;
  const int n = r0 >> 8;

  ws_s[t] = Ws[t]; ws_s[256 + t] = Ws[256 + t]; ws_s[512 + t] = bs[t];
  ha2_s[t] = ha2g[n*256 + t];
  if (t < 64) ha1_s[t] = ha1g[r0 + t];
  if (t < 128) obs_s[t >> 1][t & 1] = obs[(size_t)(r0 + (t >> 1)) * 5 + 1 + (t & 1)];
  __syncthreads();

  // single-pass softmax numerator (|x| small -> exp safe without max-sub)
  const int rr = t & 63, seg = t >> 6;
  {
    const float a1 = ha1_s[rr];
    float sum = 0.f;
    for (int c8 = 0; c8 < 8; ++c8) {
      bf16x8 pk;
#pragma unroll
      for (int e = 0; e < 8; ++e) {
        float x = a1 + ha2_s[seg*64 + c8*8 + e];
        x = fmaxf(x, 0.01f * x);          // leaky_relu
        const float ev = __expf(x);
        sum += ev;
        pk[e] = f2bf(ev);
      }
      *reinterpret_cast<bf16x8*>(&attimg[rr][seg*64 + c8*8]) = pk;
    }
    red[seg][rr] = sum;
  }
  __syncthreads();
  if (t < 64) rd_s[t] = 1.f / (red[0][t] + red[1][t] + red[2][t] + red[3][t]);
  __syncthreads();

  const int w = t >> 6, lane = t & 63, lo = lane & 15, hq = lane >> 4;
  f32x4 acc[4][4];
#pragma unroll
  for (int rt = 0; rt < 4; ++rt)
#pragma unroll
    for (int ct = 0; ct < 4; ++ct) acc[rt][ct] = (f32x4){0.f, 0.f, 0.f, 0.f};

  // MFMA1: h' = att @ h  (B prefetched from hpack, depth 1)
  {
    const short* bB = hpack + (size_t)n*65536 + ((size_t)(w*4)*64 + lane)*8;
    bf16x8 bb[4];
#pragma unroll
    for (int ct = 0; ct < 4; ++ct) bb[ct] = *reinterpret_cast<const bf16x8*>(bB + ct*512);
    for (int ks = 0; ks < 8; ++ks) {
      bf16x8 bn[4];
      if (ks < 7) {
#pragma unroll
        for (int ct = 0; ct < 4; ++ct)
          bn[ct] = *reinterpret_cast<const bf16x8*>(bB + (ks+1)*8192 + ct*512);
      }
      bf16x8 a[4];
#pragma unroll
      for (int rt = 0; rt < 4; ++rt)
        a[rt] = *reinterpret_cast<const bf16x8*>(&attimg[rt*16 + lo][ks*32 + hq*8]);
#pragma unroll
      for (int rt = 0; rt < 4; ++rt)
#pragma unroll
        for (int ct = 0; ct < 4; ++ct)
          acc[rt][ct] = __builtin_amdgcn_mfma_f32_16x16x32_bf16(a[rt], bb[ct], acc[rt][ct], 0, 0, 0);
      if (ks < 7) {
#pragma unroll
        for (int ct = 0; ct < 4; ++ct) bb[ct] = bn[ct];
      }
    }
  }
  __syncthreads();   // attimg (att) reads done

  // scaled h' into attimg
#pragma unroll
  for (int rt = 0; rt < 4; ++rt)
#pragma unroll
    for (int q = 0; q < 4; ++q) {
      const int row = rt*16 + hq*4 + q;
      const float sc = rd_s[row];
#pragma unroll
      for (int ct = 0; ct < 4; ++ct)
        attimg[row][w*64 + ct*16 + lo] = f2bf(acc[rt][ct][q] * sc);
    }
  __syncthreads();

  // MFMA2a: y += h' @ W1[0:256]
  f32x4 accY[4][4];
#pragma unroll
  for (int rt = 0; rt < 4; ++rt)
#pragma unroll
    for (int ct = 0; ct < 4; ++ct) accY[rt][ct] = (f32x4){0.f, 0.f, 0.f, 0.f};
  const short* w1B = w1p + ((size_t)(w*4)*64 + lane)*8;
  {
    bf16x8 bb[4];
#pragma unroll
    for (int ct = 0; ct < 4; ++ct) bb[ct] = *reinterpret_cast<const bf16x8*>(w1B + ct*512);
    for (int ks = 0; ks < 8; ++ks) {
      bf16x8 bn[4];
      if (ks < 7) {
#pragma unroll
        for (int ct = 0; ct < 4; ++ct)
          bn[ct] = *reinterpret_cast<const bf16x8*>(w1B + (ks+1)*8192 + ct*512);
      }
      bf16x8 a[4];
#pragma unroll
      for (int rt = 0; rt < 4; ++rt)
        a[rt] = *reinterpret_cast<const bf16x8*>(&attimg[rt*16 + lo][ks*32 + hq*8]);
#pragma unroll
      for (int rt = 0; rt < 4; ++rt)
#pragma unroll
        for (int ct = 0; ct < 4; ++ct)
          accY[rt][ct] = __builtin_amdgcn_mfma_f32_16x16x32_bf16(a[rt], bb[ct], accY[rt][ct], 0, 0, 0);
      if (ks < 7) {
#pragma unroll
        for (int ct = 0; ct < 4; ++ct) bb[ct] = bn[ct];
      }
    }
  }
  __syncthreads();   // h' reads done

  // build se into attimg (overwrites h')
  {
    const float o1 = obs_s[rr][0], o2 = obs_s[rr][1];
    for (int c8 = 0; c8 < 8; ++c8) {
      const int c = seg*64 + c8*8;
      bf16x8 pk;
#pragma unroll
      for (int e = 0; e < 8; ++e) {
        const float sv = fmaf(o2, ws_s[256 + c + e], fmaf(o1, ws_s[c + e], ws_s[512 + c + e]));
        pk[e] = f2bf(fmaxf(sv, 0.f));
      }
      *reinterpret_cast<bf16x8*>(&attimg[rr][c]) = pk;
    }
  }
  __syncthreads();

  // MFMA2b: y += se @ W1[256:512]
  {
    bf16x8 bb[4];
#pragma unroll
    for (int ct = 0; ct < 4; ++ct)
      bb[ct] = *reinterpret_cast<const bf16x8*>(w1B + 8*8192 + ct*512);
    for (int ks = 0; ks < 8; ++ks) {
      bf16x8 bn[4];
      if (ks < 7) {
#pragma unroll
        for (int ct = 0; ct < 4; ++ct)
          bn[ct] = *reinterpret_cast<const bf16x8*>(w1B + (ks+9)*8192 + ct*512);
      }
      bf16x8 a[4];
#pragma unroll
      for (int rt = 0; rt < 4; ++rt)
        a[rt] = *reinterpret_cast<const bf16x8*>(&attimg[rt*16 + lo][ks*32 + hq*8]);
#pragma unroll
      for (int rt = 0; rt < 4; ++rt)
#pragma unroll
        for (int ct = 0; ct < 4; ++ct)
          accY[rt][ct] = __builtin_amdgcn_mfma_f32_16x16x32_bf16(a[rt], bb[ct], accY[rt][ct], 0, 0, 0);
      if (ks < 7) {
#pragma unroll
        for (int ct = 0; ct < 4; ++ct) bb[ct] = bn[ct];
      }
    }
  }

  // BN1 partial sums
  float s[4] = {0,0,0,0}, ss[4] = {0,0,0,0};
#pragma unroll
  for (int rt = 0; rt < 4; ++rt)
#pragma unroll
    for (int q = 0; q < 4; ++q)
#pragma unroll
      for (int ct = 0; ct < 4; ++ct) {
        const float v = accY[rt][ct][q];
        s[ct] += v; ss[ct] += v * v;
      }
#pragma unroll
  for (int off = 16; off < 64; off <<= 1)
#pragma unroll
    for (int ct = 0; ct < 4; ++ct) {
      s[ct] += __shfl_xor(s[ct], off);
      ss[ct] += __shfl_xor(ss[ct], off);
    }
  if (hq == 0)
#pragma unroll
    for (int ct = 0; ct < 4; ++ct) {
      const int col = w*64 + ct*16 + lo;
      atomicAdd(&st[col], s[ct]);
      atomicAdd(&st[256 + col], ss[ct]);
    }
  __syncthreads();   // se reads done

  // y tile into attimg, coalesced store
#pragma unroll
  for (int rt = 0; rt < 4; ++rt)
#pragma unroll
    for (int q = 0; q < 4; ++q) {
      const int row = rt*16 + hq*4 + q;
#pragma unroll
      for (int ct = 0; ct < 4; ++ct)
        attimg[row][w*64 + ct*16 + lo] = f2bf(accY[rt][ct][q]);
    }
  __syncthreads();
  const short* img = &attimg[0][0];
#pragma unroll
  for (int j = 0; j < 8; ++j) {
    const int f = j*2048 + t*8, row = f >> 8, col = f & 255;
    *reinterpret_cast<bf16x8*>(y + (size_t)(r0 + row)*256 + col) =
        *reinterpret_cast<const bf16x8*>(img + row*264 + col);
  }
}

// ---- K5: z = relu(bn1(y)) @ W2 + BN2 sums; z stored bf16 -------------------
__global__ __launch_bounds__(256) void k5_z(
    const short* __restrict__ y, const short* __restrict__ w2p,
    const float* __restrict__ g1, const float* __restrict__ be1,
    float* __restrict__ st, short* __restrict__ zb)
{
  __shared__ __align__(16) short xs[64][264];
  __shared__ float sc_s[256], sh_s[256];
  const int t = threadIdx.x;
  const int r0 = blockIdx.x * 64;
  {
    const float mean = st[t] * (1.f / kNV);
    const float var  = st[256 + t] * (1.f / kNV) - mean * mean;
    const float sc   = g1[t] / sqrtf(var + kEps);
    sc_s[t] = sc; sh_s[t] = be1[t] - mean * sc;
  }
  __syncthreads();
#pragma unroll
  for (int j = 0; j < 8; ++j) {
    const int f = j*2048 + t*8, row = f >> 8, col = f & 255;
    bf16x8 v = *reinterpret_cast<const bf16x8*>(y + (size_t)(r0 + row)*256 + col);
    bf16x8 ov;
#pragma unroll
    for (int e = 0; e < 8; ++e) {
      const float fv = fmaf(bf2f(v[e]), sc_s[col + e], sh_s[col + e]);
      ov[e] = f2bf(fmaxf(fv, 0.f));
    }
    *reinterpret_cast<bf16x8*>(&xs[row][col]) = ov;
  }
  __syncthreads();

  const int w = t >> 6, lane = t & 63, lo = lane & 15, hq = lane >> 4;
  f32x4 acc[4][2];
#pragma unroll
  for (int rt = 0; rt < 4; ++rt)
#pragma unroll
    for (int ct = 0; ct < 2; ++ct) acc[rt][ct] = (f32x4){0.f, 0.f, 0.f, 0.f};

  {
    const short* w2B = w2p + ((size_t)(w*2)*64 + lane)*8;
    bf16x8 bb[2];
#pragma unroll
    for (int ct = 0; ct < 2; ++ct) bb[ct] = *reinterpret_cast<const bf16x8*>(w2B + ct*512);
    for (int ks = 0; ks < 8; ++ks) {
      bf16x8 bn[2];
      if (ks < 7) {
#pragma unroll
        for (int ct = 0; ct < 2; ++ct)
          bn[ct] = *reinterpret_cast<const bf16x8*>(w2B + (ks+1)*4096 + ct*512);
      }
      bf16x8 a[4];
#pragma unroll
      for (int rt = 0; rt < 4; ++rt)
        a[rt] = *reinterpret_cast<const bf16x8*>(&xs[rt*16 + lo][ks*32 + hq*8]);
#pragma unroll
      for (int rt = 0; rt < 4; ++rt)
#pragma unroll
        for (int ct = 0; ct < 2; ++ct)
          acc[rt][ct] = __builtin_amdgcn_mfma_f32_16x16x32_bf16(a[rt], bb[ct], acc[rt][ct], 0, 0, 0);
      if (ks < 7) {
#pragma unroll
        for (int ct = 0; ct < 2; ++ct) bb[ct] = bn[ct];
      }
    }
  }

  float s[2] = {0,0}, ss[2] = {0,0};
#pragma unroll
  for (int rt = 0; rt < 4; ++rt)
#pragma unroll
    for (int q = 0; q < 4; ++q)
#pragma unroll
      for (int ct = 0; ct < 2; ++ct) {
        const float v = acc[rt][ct][q];
        s[ct] += v; ss[ct] += v * v;
      }
#pragma unroll
  for (int off = 16; off < 64; off <<= 1)
#pragma unroll
    for (int ct = 0; ct < 2; ++ct) {
      s[ct] += __shfl_xor(s[ct], off);
      ss[ct] += __shfl_xor(ss[ct], off);
    }
  if (hq == 0)
#pragma unroll
    for (int ct = 0; ct < 2; ++ct) {
      const int col = w*32 + ct*16 + lo;
      atomicAdd(&st[1024 + col], s[ct]);
      atomicAdd(&st[1152 + col], ss[ct]);
    }
  __syncthreads();   // xs reads done

  // bf16 z tile (stride 136), coalesced store
  short* zimg = reinterpret_cast<short*>(&xs[0][0]);
#pragma unroll
  for (int rt = 0; rt < 4; ++rt)
#pragma unroll
    for (int q = 0; q < 4; ++q) {
      const int row = rt*16 + hq*4 + q;
#pragma unroll
      for (int ct = 0; ct < 2; ++ct)
        zimg[row*136 + w*32 + ct*16 + lo] = f2bf(acc[rt][ct][q]);
    }
  __syncthreads();
#pragma unroll
  for (int j = 0; j < 4; ++j) {
    const int f = j*2048 + t*8, row = f >> 7, col = f & 127;
    *reinterpret_cast<bf16x8*>(zb + (size_t)(r0 + row)*128 + col) =
        *reinterpret_cast<const bf16x8*>(zimg + row*136 + col);
  }
}

// ---- K7: out = relu(bn2(z)) -- bf16 in, fp32 out ---------------------------
__global__ __launch_bounds__(256) void k7_out(
    const short* __restrict__ zb, const float* __restrict__ st,
    const float* __restrict__ g2, const float* __restrict__ be2,
    float* __restrict__ out)
{
  __shared__ float sc_s[128], sh_s[128];
  const int t = threadIdx.x;
  if (t < 128) {
    const float mean = st[1024 + t] * (1.f / kNV);
    const float var  = st[1152 + t] * (1.f / kNV) - mean * mean;
    const float sc   = g2[t] / sqrtf(var + kEps);
    sc_s[t] = sc; sh_s[t] = be2[t] - mean * sc;
  }
  __syncthreads();
#pragma unroll
  for (int j = 0; j < 2; ++j) {
    const size_t u = (size_t)blockIdx.x * 512 + j*256 + t;  // 8-elem unit
    bf16x8 v = *reinterpret_cast<const bf16x8*>(zb + u*8);
    const int col = ((int)u & 15) * 8;
    float4 r0, r1;
    r0.x = fmaxf(fmaf(bf2f(v[0]), sc_s[col+0], sh_s[col+0]), 0.f);
    r0.y = fmaxf(fmaf(bf2f(v[1]), sc_s[col+1], sh_s[col+1]), 0.f);
    r0.z = fmaxf(fmaf(bf2f(v[2]), sc_s[col+2], sh_s[col+2]), 0.f);
    r0.w = fmaxf(fmaf(bf2f(v[3]), sc_s[col+3], sh_s[col+3]), 0.f);
    r1.x = fmaxf(fmaf(bf2f(v[4]), sc_s[col+4], sh_s[col+4]), 0.f);
    r1.y = fmaxf(fmaf(bf2f(v[5]), sc_s[col+5], sh_s[col+5]), 0.f);
    r1.z = fmaxf(fmaf(bf2f(v[6]), sc_s[col+6], sh_s[col+6]), 0.f);
    r1.w = fmaxf(fmaf(bf2f(v[7]), sc_s[col+7], sh_s[col+7]), 0.f);
    *reinterpret_cast<float4*>(out + u*8)     = r0;
    *reinterpret_cast<float4*>(out + u*8 + 4) = r1;
  }
}

} // namespace

extern "C" void kernel_launch(void* const* d_in, const int* in_sizes, int n_in,
                              void* d_out, int out_size, void* d_ws, size_t ws_size,
                              hipStream_t stream) {
  const float* obs = (const float*)d_in[0];
  const float* hin = (const float*)d_in[1];
  const float* Ws  = (const float*)d_in[2];
  const float* bs  = (const float*)d_in[3];
  const float* Wv  = (const float*)d_in[4];
  const float* bv  = (const float*)d_in[5];
  const float* Wg  = (const float*)d_in[6];
  const float* a_w = (const float*)d_in[7];
  const float* W1  = (const float*)d_in[8];
  // d_in[9] = b1: cancels in batchnorm
  const float* g1  = (const float*)d_in[10];
  const float* be1 = (const float*)d_in[11];
  const float* W2  = (const float*)d_in[12];
  // d_in[13] = b2: cancels in batchnorm
  const float* g2  = (const float*)d_in[14];
  const float* be2 = (const float*)d_in[15];

  char* base = (char*)d_ws;
  short* hpack = (short*)(base);                 // 33.5 MB
  short* y     = (short*)(base + 33554432);      // 33.5 MB
  short* zb    = (short*)(base + 67108864);      // 16.8 MB
  float* ha1   = (float*)(base + 83886080);      // 256 KB
  float* ha2   = (float*)(base + 84148224);      // 256 KB
  float* st    = (float*)(base + 84410368);      // 6 KB
  short* wgp   = (short*)(base + 84416512);      // 288 KB
  short* w1p   = (short*)(base + 84711424);      // 256 KB
  short* w2p   = (short*)(base + 84973568);      // 64 KB
  short* wgab  = (short*)(base + 85039104);      // 2.3 KB
  float* out   = (float*)d_out;

  kpack       <<<160,  256, 0, stream>>>(Wg, W1, W2, a_w, wgp, w1p, w2p, wgab, st);
  k1_encode   <<<2048, 256, 0, stream>>>(obs, hin, Ws, bs, Wv, bv, wgp, wgab, hpack, ha1, ha2);
  k23_attn_fc1<<<1024, 256, 0, stream>>>(ha1, ha2, hpack, obs, Ws, bs, w1p, y, st);
  k5_z        <<<1024, 256, 0, stream>>>(y, w2p, g1, be1, st, zb);
  k7_out      <<<2048, 256, 0, stream>>>(zb, st, g2, be2, out);
}